// Round 2
// baseline (358.642 us; speedup 1.0000x reference)
//
#include <hip/hip_runtime.h>
#include <cstdint>
#include <cstddef>

// ---------- types ----------
typedef __attribute__((ext_vector_type(8))) __bf16 bf16x8;
typedef __attribute__((ext_vector_type(4))) float f32x4;

// fp32 -> bf16 round-to-nearest-even
__device__ __forceinline__ unsigned short f2bf(float x) {
    unsigned int u = __float_as_uint(x);
    u += 0x7fffu + ((u >> 16) & 1u);
    return (unsigned short)(u >> 16);
}

typedef const __attribute__((address_space(1))) void* gptr_t;
typedef __attribute__((address_space(3))) void* lptr_t;
__device__ __forceinline__ void gload_lds16(const void* g, void* l) {
    __builtin_amdgcn_global_load_lds((gptr_t)g, (lptr_t)l, 16, 0, 0);
}

// ---------- cast + transpose weight: Wt[n][k] = W[k][n] ----------
__global__ __launch_bounds__(256) void transpose_cast_kernel(const float* __restrict__ W,
                                                             unsigned short* __restrict__ Wt,
                                                             int D) {
    int idx = blockIdx.x * 256 + threadIdx.x;  // k*D + n
    int k = idx / D, n = idx % D;
    Wt[n * D + k] = f2bf(W[idx]);
}

// ---------- GEMM, C = A * B with Bt = B^T given ----------
// A [M,K] row-major (fp32 if AF32 else bf16), Bt [N,K] bf16 row-major,
// C [M,N] (bf16 if OUTBF else f32).
// 128x128 tile, BK=32, 4 waves, each wave 64x64 (4x4 fragments of 16x16x32)
template <int AF32, int OUTBF>
__global__ __launch_bounds__(256) void gemm_bt(const void* __restrict__ Ain,
                                               const unsigned short* __restrict__ Bt,
                                               void* __restrict__ Cout,
                                               int M, int N, int K) {
    // Au: f32 path uses 16KB as float[8 kq][128 row][4]; bf16 path uses 8KB as ushort[128][32]
    __shared__ __align__(16) unsigned short Au[128 * 64];
    __shared__ __align__(16) unsigned short Bs[128 * 32];
    const int tid = threadIdx.x;
    const int w = tid >> 6;
    const int lane = tid & 63;
    const int m0 = blockIdx.y * 128;
    const int n0 = blockIdx.x * 128;
    const int wr = w >> 1, wc = w & 1;

    f32x4 acc[4][4];
#pragma unroll
    for (int i = 0; i < 4; ++i)
#pragma unroll
        for (int j = 0; j < 4; ++j) acc[i][j] = f32x4{0.f, 0.f, 0.f, 0.f};

    for (int kt = 0; kt < K; kt += 32) {
        // ---- stage A tile ----
        if (AF32) {
            const float* A = (const float*)Ain;
            // 1024 segments of 16B; LDS layout seg = kq*128 + row (kq-major)
#pragma unroll
            for (int p = 0; p < 4; ++p) {
                int seg = p * 256 + tid;          // wave-linear
                int kq = seg >> 7, row = seg & 127;
                gload_lds16(A + (size_t)(m0 + row) * K + kt + kq * 4,
                            &Au[(p * 256 + w * 64) * 8]);
            }
        } else {
            const unsigned short* A = (const unsigned short*)Ain;
#pragma unroll
            for (int p = 0; p < 2; ++p) {
                int c = p * 4 + w;
                int row = c * 16 + (lane >> 2);
                gload_lds16(A + (size_t)(m0 + row) * K + kt + (lane & 3) * 8,
                            &Au[c * 512]);
            }
        }
        // ---- stage Bt tile (bf16, row-major [128][32]) ----
#pragma unroll
        for (int p = 0; p < 2; ++p) {
            int c = p * 4 + w;
            int row = c * 16 + (lane >> 2);
            gload_lds16(Bt + (size_t)(n0 + row) * K + kt + (lane & 3) * 8,
                        &Bs[c * 512]);
        }
        __syncthreads();

        // ---- fragments ----
        bf16x8 af[4], bfr[4];
        if (AF32) {
            const float* Asf = (const float*)Au;
            const int kq0 = (lane >> 4) * 2;
#pragma unroll
            for (int m = 0; m < 4; ++m) {
                int row = wr * 64 + m * 16 + (lane & 15);
                f32x4 a0 = *(const f32x4*)&Asf[(kq0 * 128 + row) * 4];
                f32x4 a1 = *(const f32x4*)&Asf[((kq0 + 1) * 128 + row) * 4];
                union { bf16x8 v; unsigned short u[8]; } cv;
#pragma unroll
                for (int j = 0; j < 4; ++j) {
                    cv.u[j] = f2bf(a0[j]);
                    cv.u[j + 4] = f2bf(a1[j]);
                }
                af[m] = cv.v;
            }
        } else {
#pragma unroll
            for (int m = 0; m < 4; ++m)
                af[m] = *(const bf16x8*)&Au[(wr * 64 + m * 16 + (lane & 15)) * 32 +
                                            (lane >> 4) * 8];
        }
#pragma unroll
        for (int n = 0; n < 4; ++n)
            bfr[n] = *(const bf16x8*)&Bs[(wc * 64 + n * 16 + (lane & 15)) * 32 +
                                         (lane >> 4) * 8];
#pragma unroll
        for (int m = 0; m < 4; ++m)
#pragma unroll
            for (int n = 0; n < 4; ++n)
                acc[m][n] = __builtin_amdgcn_mfma_f32_16x16x32_bf16(af[m], bfr[n], acc[m][n], 0, 0, 0);
        __syncthreads();
    }

    const int crow = (lane >> 4) * 4;
    const int ccol = lane & 15;
#pragma unroll
    for (int m = 0; m < 4; ++m) {
#pragma unroll
        for (int n = 0; n < 4; ++n) {
            int r0 = m0 + wr * 64 + m * 16 + crow;
            int c0 = n0 + wc * 64 + n * 16 + ccol;
#pragma unroll
            for (int j = 0; j < 4; ++j) {
                if (OUTBF)
                    ((unsigned short*)Cout)[(size_t)(r0 + j) * N + c0] = f2bf(acc[m][n][j]);
                else
                    ((float*)Cout)[(size_t)(r0 + j) * N + c0] = acc[m][n][j];
            }
        }
    }
}

// ---------- causal flash attention ----------
// Q,K,V,O: bf16 [B*L, 1024] row-major (head h occupies cols h*64..h*64+64)
// O may alias Q: each block reads only its own 64 Q rows (before any write)
// and writes exactly those rows at the end.
__global__ __launch_bounds__(256) void flash_kernel(const unsigned short* __restrict__ Qg,
                                                    const unsigned short* __restrict__ Kg,
                                                    const unsigned short* __restrict__ Vg,
                                                    unsigned short* __restrict__ Og) {
    __shared__ __align__(16) unsigned short Ks[64 * 72];      // [kv][d], +8 pad
    __shared__ __align__(16) unsigned short Vs[64 * 72];      // [d][kv], +8 pad
    __shared__ __align__(16) unsigned short Ps[4][16 * 72];   // per-wave P tile

    const int tid = threadIdx.x;
    const int w = tid >> 6;
    const int lane = tid & 63;
    const int bh = blockIdx.y;          // 0..31
    const int b = bh >> 4, h = bh & 15;
    const int qblk = blockIdx.x * 64;
    const int q0 = qblk + w * 16;
    const int rowbase = b * 2048;
    const int hd0 = h * 64;

    // Q fragments (A-operand), 2 k-steps of 32 over hd=64
    bf16x8 qf[2];
#pragma unroll
    for (int st = 0; st < 2; ++st)
        qf[st] = *(const bf16x8*)(Qg + (size_t)(rowbase + q0 + (lane & 15)) * 1024 + hd0 +
                                  st * 32 + (lane >> 4) * 8);

    float m_prev[4], lsum[4];
    f32x4 oacc[4];
#pragma unroll
    for (int j = 0; j < 4; ++j) { m_prev[j] = -1e30f; lsum[j] = 0.f; }
#pragma unroll
    for (int n = 0; n < 4; ++n) oacc[n] = f32x4{0.f, 0.f, 0.f, 0.f};

    const int nt = qblk / 64 + 1;  // causal: only tiles with kv0 <= qblk
    for (int t = 0; t < nt; ++t) {
        const int kv0 = t * 64;
        // ---- stage K (row-major) and V (transposed) ----
#pragma unroll
        for (int p = 0; p < 2; ++p) {
            int r = p * 32 + (tid >> 3);
            int c0 = (tid & 7) * 8;
            size_t gidx = (size_t)(rowbase + kv0 + r) * 1024 + hd0 + c0;
            bf16x8 kvv = *(const bf16x8*)(Kg + gidx);
            *(bf16x8*)&Ks[r * 72 + c0] = kvv;
            bf16x8 vv = *(const bf16x8*)(Vg + gidx);
#pragma unroll
            for (int jj = 0; jj < 8; ++jj)
                Vs[(c0 + jj) * 72 + r] = ((const unsigned short*)&vv)[jj];
        }
        __syncthreads();

        // ---- S = Q K^T (16 x 64) ----
        f32x4 sacc[4];
#pragma unroll
        for (int n = 0; n < 4; ++n) {
            bf16x8 k0 = *(const bf16x8*)&Ks[(n * 16 + (lane & 15)) * 72 + (lane >> 4) * 8];
            bf16x8 k1 = *(const bf16x8*)&Ks[(n * 16 + (lane & 15)) * 72 + 32 + (lane >> 4) * 8];
            f32x4 c = f32x4{0.f, 0.f, 0.f, 0.f};
            c = __builtin_amdgcn_mfma_f32_16x16x32_bf16(qf[0], k0, c, 0, 0, 0);
            c = __builtin_amdgcn_mfma_f32_16x16x32_bf16(qf[1], k1, c, 0, 0, 0);
            sacc[n] = c;
        }

        // ---- online softmax (per row j) ----
#pragma unroll
        for (int j = 0; j < 4; ++j) {
            int row = q0 + (lane >> 4) * 4 + j;
            float sv[4];
            float tmax = -1e30f;
#pragma unroll
            for (int n = 0; n < 4; ++n) {
                int col = kv0 + n * 16 + (lane & 15);
                float v = sacc[n][j] * 0.125f;
                if (col > row) v = -1e30f;
                sv[n] = v;
                tmax = fmaxf(tmax, v);
            }
#pragma unroll
            for (int off = 8; off >= 1; off >>= 1)
                tmax = fmaxf(tmax, __shfl_xor(tmax, off, 16));
            float mnew = fmaxf(m_prev[j], tmax);
            float alpha = __expf(m_prev[j] - mnew);
            float psum = 0.f;
#pragma unroll
            for (int n = 0; n < 4; ++n) {
                float p = __expf(sv[n] - mnew);
                psum += p;
                Ps[w][((lane >> 4) * 4 + j) * 72 + n * 16 + (lane & 15)] = f2bf(p);
            }
#pragma unroll
            for (int off = 8; off >= 1; off >>= 1)
                psum += __shfl_xor(psum, off, 16);
            lsum[j] = lsum[j] * alpha + psum;
            m_prev[j] = mnew;
#pragma unroll
            for (int n = 0; n < 4; ++n) oacc[n][j] *= alpha;
        }

        // compiler fence: Ps writes above must not be reordered past the reads below
        asm volatile("" ::: "memory");

        // ---- O += P V ---- (DS ops complete in-order within a wave)
#pragma unroll
        for (int st = 0; st < 2; ++st) {
            bf16x8 pa = *(const bf16x8*)&Ps[w][(lane & 15) * 72 + st * 32 + (lane >> 4) * 8];
#pragma unroll
            for (int n = 0; n < 4; ++n) {
                bf16x8 vfr = *(const bf16x8*)&Vs[(n * 16 + (lane & 15)) * 72 + st * 32 + (lane >> 4) * 8];
                oacc[n] = __builtin_amdgcn_mfma_f32_16x16x32_bf16(pa, vfr, oacc[n], 0, 0, 0);
            }
        }
        __syncthreads();
    }

    // ---- normalize and write O (in-place over this block's own Q rows) ----
#pragma unroll
    for (int n = 0; n < 4; ++n) {
#pragma unroll
        for (int j = 0; j < 4; ++j) {
            int row = q0 + (lane >> 4) * 4 + j;
            int col = hd0 + n * 16 + (lane & 15);
            Og[(size_t)(rowbase + row) * 1024 + col] = f2bf(oacc[n][j] / lsum[j]);
        }
    }
}

// ---------- launch ----------
extern "C" void kernel_launch(void* const* d_in, const int* in_sizes, int n_in,
                              void* d_out, int out_size, void* d_ws, size_t ws_size,
                              hipStream_t stream) {
    const float* x  = (const float*)d_in[0];
    const float* Wq = (const float*)d_in[1];
    const float* Wk = (const float*)d_in[2];
    const float* Wv = (const float*)d_in[3];
    const float* Wo = (const float*)d_in[4];
    float* out = (float*)d_out;

    const int XN = 4096 * 1024;   // B*L*D elements
    const int WN = 1024 * 1024;

    // workspace layout: 4 transposed weights (8MB) + Q,K,V (24MB) = 32MB total.
    // O is written in-place over Q by flash_kernel (safe: per-block row ownership).
    unsigned short* ws  = (unsigned short*)d_ws;
    unsigned short* Wqt = ws;
    unsigned short* Wkt = Wqt + WN;
    unsigned short* Wvt = Wkt + WN;
    unsigned short* Wot = Wvt + WN;
    unsigned short* Qbf = Wot + WN;
    unsigned short* Kbf = Qbf + XN;
    unsigned short* Vbf = Kbf + XN;
    unsigned short* Obf = Qbf;  // alias

    transpose_cast_kernel<<<WN / 256, 256, 0, stream>>>(Wq, Wqt, 1024);
    transpose_cast_kernel<<<WN / 256, 256, 0, stream>>>(Wk, Wkt, 1024);
    transpose_cast_kernel<<<WN / 256, 256, 0, stream>>>(Wv, Wvt, 1024);
    transpose_cast_kernel<<<WN / 256, 256, 0, stream>>>(Wo, Wot, 1024);

    dim3 gg(1024 / 128, 4096 / 128);  // (N/BN, M/BM)
    gemm_bt<1, 1><<<gg, 256, 0, stream>>>(x, Wqt, Qbf, 4096, 1024, 1024);
    gemm_bt<1, 1><<<gg, 256, 0, stream>>>(x, Wkt, Kbf, 4096, 1024, 1024);
    gemm_bt<1, 1><<<gg, 256, 0, stream>>>(x, Wvt, Vbf, 4096, 1024, 1024);

    flash_kernel<<<dim3(2048 / 64, 32), 256, 0, stream>>>(Qbf, Kbf, Vbf, Obf);

    gemm_bt<0, 0><<<gg, 256, 0, stream>>>(Obf, Wot, out, 4096, 1024, 1024);
}

// Round 3
// 226.460 us; speedup vs baseline: 1.5837x; 1.5837x over previous
//
#include <hip/hip_runtime.h>
#include <cstdint>
#include <cstddef>

// ---------- types ----------
typedef __attribute__((ext_vector_type(8))) __bf16 bf16x8;
typedef __attribute__((ext_vector_type(4))) float f32x4;

// fp32 -> bf16 round-to-nearest-even
__device__ __forceinline__ unsigned short f2bf(float x) {
    unsigned int u = __float_as_uint(x);
    u += 0x7fffu + ((u >> 16) & 1u);
    return (unsigned short)(u >> 16);
}

typedef const __attribute__((address_space(1))) void* gptr_t;
typedef __attribute__((address_space(3))) void* lptr_t;
__device__ __forceinline__ void gload_lds16(const void* g, void* l) {
    __builtin_amdgcn_global_load_lds((gptr_t)g, (lptr_t)l, 16, 0, 0);
}

// ---------- cast + transpose weight: Wt[n][k] = W[k][n] * scale ----------
__global__ __launch_bounds__(256) void transpose_cast_kernel(const float* __restrict__ W,
                                                             unsigned short* __restrict__ Wt,
                                                             int D, float scale) {
    int idx = blockIdx.x * 256 + threadIdx.x;  // k*D + n
    int k = idx / D, n = idx % D;
    Wt[n * D + k] = f2bf(W[idx] * scale);
}

// ---------- GEMM, C = A * B with Bt = B^T given ----------
// A [M,K] row stride lda (fp32 if AF32 else bf16), Bt [N,K] bf16 row-major (stride K),
// C [M,N] row stride ldc (bf16 if OUTBF else f32).
// 128x128 tile, BK=32, 4 waves, each wave 64x64 (4x4 fragments of 16x16x32)
template <int AF32, int OUTBF>
__global__ __launch_bounds__(256) void gemm_bt(const void* __restrict__ Ain,
                                               const unsigned short* __restrict__ Bt,
                                               void* __restrict__ Cout,
                                               int M, int N, int K, int lda, int ldc) {
    // f32 A path: 16KB as float[8 kq][128 row][4]; bf16 path: 8KB as ushort[128][32]
    __shared__ __align__(16) unsigned short Au[AF32 ? 128 * 64 : 128 * 32];
    __shared__ __align__(16) unsigned short Bs[128 * 32];
    const int tid = threadIdx.x;
    const int w = tid >> 6;
    const int lane = tid & 63;
    const int m0 = blockIdx.y * 128;
    const int n0 = blockIdx.x * 128;
    const int wr = w >> 1, wc = w & 1;

    f32x4 acc[4][4];
#pragma unroll
    for (int i = 0; i < 4; ++i)
#pragma unroll
        for (int j = 0; j < 4; ++j) acc[i][j] = f32x4{0.f, 0.f, 0.f, 0.f};

    for (int kt = 0; kt < K; kt += 32) {
        // ---- stage A tile ----
        if (AF32) {
            const float* A = (const float*)Ain;
#pragma unroll
            for (int p = 0; p < 4; ++p) {
                int seg = p * 256 + tid;          // seg = kq*128 + row, kq-major
                int kq = seg >> 7, row = seg & 127;
                gload_lds16(A + (size_t)(m0 + row) * lda + kt + kq * 4,
                            &Au[(p * 256 + w * 64) * 8]);
            }
        } else {
            const unsigned short* A = (const unsigned short*)Ain;
#pragma unroll
            for (int p = 0; p < 2; ++p) {
                int c = p * 4 + w;
                int row = c * 16 + (lane >> 2);
                gload_lds16(A + (size_t)(m0 + row) * lda + kt + (lane & 3) * 8,
                            &Au[c * 512]);
            }
        }
        // ---- stage Bt tile (bf16, row-major [128][32]) ----
#pragma unroll
        for (int p = 0; p < 2; ++p) {
            int c = p * 4 + w;
            int row = c * 16 + (lane >> 2);
            gload_lds16(Bt + (size_t)(n0 + row) * K + kt + (lane & 3) * 8,
                        &Bs[c * 512]);
        }
        __syncthreads();

        // ---- fragments ----
        bf16x8 af[4], bfr[4];
        if (AF32) {
            const float* Asf = (const float*)Au;
            const int kq0 = (lane >> 4) * 2;
#pragma unroll
            for (int m = 0; m < 4; ++m) {
                int row = wr * 64 + m * 16 + (lane & 15);
                f32x4 a0 = *(const f32x4*)&Asf[(kq0 * 128 + row) * 4];
                f32x4 a1 = *(const f32x4*)&Asf[((kq0 + 1) * 128 + row) * 4];
                union { bf16x8 v; unsigned short u[8]; } cv;
#pragma unroll
                for (int j = 0; j < 4; ++j) {
                    cv.u[j] = f2bf(a0[j]);
                    cv.u[j + 4] = f2bf(a1[j]);
                }
                af[m] = cv.v;
            }
        } else {
#pragma unroll
            for (int m = 0; m < 4; ++m)
                af[m] = *(const bf16x8*)&Au[(wr * 64 + m * 16 + (lane & 15)) * 32 +
                                            (lane >> 4) * 8];
        }
#pragma unroll
        for (int n = 0; n < 4; ++n)
            bfr[n] = *(const bf16x8*)&Bs[(wc * 64 + n * 16 + (lane & 15)) * 32 +
                                         (lane >> 4) * 8];
#pragma unroll
        for (int m = 0; m < 4; ++m)
#pragma unroll
            for (int n = 0; n < 4; ++n)
                acc[m][n] = __builtin_amdgcn_mfma_f32_16x16x32_bf16(af[m], bfr[n], acc[m][n], 0, 0, 0);
        __syncthreads();
    }

    const int crow = (lane >> 4) * 4;
    const int ccol = lane & 15;
#pragma unroll
    for (int m = 0; m < 4; ++m) {
#pragma unroll
        for (int n = 0; n < 4; ++n) {
            int r0 = m0 + wr * 64 + m * 16 + crow;
            int c0 = n0 + wc * 64 + n * 16 + ccol;
#pragma unroll
            for (int j = 0; j < 4; ++j) {
                if (OUTBF)
                    ((unsigned short*)Cout)[(size_t)(r0 + j) * ldc + c0] = f2bf(acc[m][n][j]);
                else
                    ((float*)Cout)[(size_t)(r0 + j) * ldc + c0] = acc[m][n][j];
            }
        }
    }
}

// ---------- causal flash attention ----------
// QKV fused [B*L, 3072] bf16: Q cols [0,1024), K cols [1024,2048), V cols [2048,3072).
// Q is pre-scaled by 1/sqrt(hd) (folded into Wq).
// O written in-place over the Q columns (each block reads only its own Q rows,
// before writing them; K/V columns never overlap O).
// Grid (16, 32): block x=i processes qblk i then 31-i -> constant 33 KV tiles.
__global__ __launch_bounds__(256) void flash_kernel(unsigned short* __restrict__ QKV) {
    __shared__ __align__(16) unsigned short Ks[64 * 72];      // [kv][d], +8 pad
    __shared__ __align__(16) unsigned short Vs[64 * 72];      // [d][kv], kv XOR-swizzled
    __shared__ __align__(16) unsigned short Ps[4][16 * 72];   // per-wave P tile

    const int tid = threadIdx.x;
    const int w = tid >> 6;
    const int lane = tid & 63;
    const int bh = blockIdx.y;          // 0..31
    const int b = bh >> 4, h = bh & 15;
    const int rowbase = b * 2048;
    const int hd0 = h * 64;
    const int S = 3072;

    // staging indices: thread covers K rows {p*32+sr}, cols [sc, sc+8)
    const int sr = tid >> 3;            // 0..31
    const int sc = (tid & 7) * 8;       // 0..56
    const int vswz = (tid & 7) << 3;    // V store column swizzle = (d>>3)&7 for d in [sc,sc+8)

    for (int phase = 0; phase < 2; ++phase) {
        const int qblk = (phase == 0 ? (int)blockIdx.x : 31 - (int)blockIdx.x) * 64;
        const int q0 = qblk + w * 16;
        const int nt = qblk / 64 + 1;

        // Q fragments (A-operand), 2 k-steps of 32 over hd=64
        bf16x8 qf[2];
#pragma unroll
        for (int st = 0; st < 2; ++st)
            qf[st] = *(const bf16x8*)(QKV + (size_t)(rowbase + q0 + (lane & 15)) * S + hd0 +
                                      st * 32 + (lane >> 4) * 8);

        float m_prev[4], lsum[4];
        f32x4 oacc[4];
#pragma unroll
        for (int j = 0; j < 4; ++j) { m_prev[j] = -1e30f; lsum[j] = 0.f; }
#pragma unroll
        for (int n = 0; n < 4; ++n) oacc[n] = f32x4{0.f, 0.f, 0.f, 0.f};

        // prologue: load KV tile 0 into registers
        bf16x8 kreg[2], vreg[2];
#pragma unroll
        for (int p = 0; p < 2; ++p) {
            size_t gi = (size_t)(rowbase + p * 32 + sr) * S + hd0 + sc;
            kreg[p] = *(const bf16x8*)(QKV + gi + 1024);
            vreg[p] = *(const bf16x8*)(QKV + gi + 2048);
        }

        for (int t = 0; t < nt; ++t) {
            __syncthreads();   // all waves done reading LDS of previous tile
            // ---- write staged regs to LDS ----
#pragma unroll
            for (int p = 0; p < 2; ++p) {
                int r = p * 32 + sr;
                *(bf16x8*)&Ks[r * 72 + sc] = kreg[p];
                int rs = r ^ vswz;
#pragma unroll
                for (int jj = 0; jj < 8; ++jj)
                    Vs[(sc + jj) * 72 + rs] = ((const unsigned short*)&vreg[p])[jj];
            }
            __syncthreads();
            // ---- issue next tile's global loads (latency hidden under compute) ----
            if (t + 1 < nt) {
#pragma unroll
                for (int p = 0; p < 2; ++p) {
                    size_t gi = (size_t)(rowbase + (t + 1) * 64 + p * 32 + sr) * S + hd0 + sc;
                    kreg[p] = *(const bf16x8*)(QKV + gi + 1024);
                    vreg[p] = *(const bf16x8*)(QKV + gi + 2048);
                }
            }

            // ---- S = Q K^T (16 x 64) ----
            f32x4 sacc[4];
#pragma unroll
            for (int n = 0; n < 4; ++n) {
                bf16x8 k0 = *(const bf16x8*)&Ks[(n * 16 + (lane & 15)) * 72 + (lane >> 4) * 8];
                bf16x8 k1 = *(const bf16x8*)&Ks[(n * 16 + (lane & 15)) * 72 + 32 + (lane >> 4) * 8];
                f32x4 c = f32x4{0.f, 0.f, 0.f, 0.f};
                c = __builtin_amdgcn_mfma_f32_16x16x32_bf16(qf[0], k0, c, 0, 0, 0);
                c = __builtin_amdgcn_mfma_f32_16x16x32_bf16(qf[1], k1, c, 0, 0, 0);
                sacc[n] = c;
            }

            // ---- online softmax (per row j); mask only on the diagonal tile ----
            const bool diag = (t == nt - 1);
#pragma unroll
            for (int j = 0; j < 4; ++j) {
                int rr = w * 16 + (lane >> 4) * 4 + j;   // row - qblk
                float sv[4];
                float tmax = -1e30f;
#pragma unroll
                for (int n = 0; n < 4; ++n) {
                    float v = sacc[n][j];
                    if (diag) {
                        int cc = n * 16 + (lane & 15);   // col - kv0
                        if (cc > rr) v = -1e30f;
                    }
                    sv[n] = v;
                    tmax = fmaxf(tmax, v);
                }
#pragma unroll
                for (int off = 8; off >= 1; off >>= 1)
                    tmax = fmaxf(tmax, __shfl_xor(tmax, off, 16));
                float mnew = fmaxf(m_prev[j], tmax);
                float alpha = __expf(m_prev[j] - mnew);
                float psum = 0.f;
#pragma unroll
                for (int n = 0; n < 4; ++n) {
                    float p = __expf(sv[n] - mnew);
                    psum += p;
                    Ps[w][((lane >> 4) * 4 + j) * 72 + n * 16 + (lane & 15)] = f2bf(p);
                }
#pragma unroll
                for (int off = 8; off >= 1; off >>= 1)
                    psum += __shfl_xor(psum, off, 16);
                lsum[j] = lsum[j] * alpha + psum;
                m_prev[j] = mnew;
#pragma unroll
                for (int n = 0; n < 4; ++n) oacc[n][j] *= alpha;
            }

            // compile-time fence: Ps writes must precede the reads below
            asm volatile("" ::: "memory");

            // ---- O += P V ---- (DS ops complete in-order within a wave)
#pragma unroll
            for (int st = 0; st < 2; ++st) {
                bf16x8 pa = *(const bf16x8*)&Ps[w][(lane & 15) * 72 + st * 32 + (lane >> 4) * 8];
#pragma unroll
                for (int n = 0; n < 4; ++n) {
                    int d = n * 16 + (lane & 15);
                    int o = (st * 32 + (lane >> 4) * 8) ^ (((d >> 3) & 7) << 3);
                    bf16x8 vfr = *(const bf16x8*)&Vs[d * 72 + o];
                    oacc[n] = __builtin_amdgcn_mfma_f32_16x16x32_bf16(pa, vfr, oacc[n], 0, 0, 0);
                }
            }
        }

        // ---- normalize and write O over this block's own Q rows ----
#pragma unroll
        for (int n = 0; n < 4; ++n) {
#pragma unroll
            for (int j = 0; j < 4; ++j) {
                int row = q0 + (lane >> 4) * 4 + j;
                int col = hd0 + n * 16 + (lane & 15);
                QKV[(size_t)(rowbase + row) * S + col] = f2bf(oacc[n][j] / lsum[j]);
            }
        }
        __syncthreads();   // phase isolation for LDS reuse
    }
}

// ---------- launch ----------
extern "C" void kernel_launch(void* const* d_in, const int* in_sizes, int n_in,
                              void* d_out, int out_size, void* d_ws, size_t ws_size,
                              hipStream_t stream) {
    const float* x  = (const float*)d_in[0];
    const float* Wq = (const float*)d_in[1];
    const float* Wk = (const float*)d_in[2];
    const float* Wv = (const float*)d_in[3];
    const float* Wo = (const float*)d_in[4];
    float* out = (float*)d_out;

    const int WN = 1024 * 1024;

    // workspace: Wqkv_t [3072][1024] (6MB) + Wo_t (2MB) + QKV [4096][3072] (24MB) = 32MB
    unsigned short* ws   = (unsigned short*)d_ws;
    unsigned short* Wqkv = ws;                 // rows 0..1023 Wq^T*scale, 1024.. Wk^T, 2048.. Wv^T
    unsigned short* Wot  = Wqkv + 3 * WN;
    unsigned short* QKV  = Wot + WN;

    transpose_cast_kernel<<<WN / 256, 256, 0, stream>>>(Wq, Wqkv,          1024, 0.125f);
    transpose_cast_kernel<<<WN / 256, 256, 0, stream>>>(Wk, Wqkv + WN,     1024, 1.0f);
    transpose_cast_kernel<<<WN / 256, 256, 0, stream>>>(Wv, Wqkv + 2 * WN, 1024, 1.0f);
    transpose_cast_kernel<<<WN / 256, 256, 0, stream>>>(Wo, Wot,           1024, 1.0f);

    // fused QKV projection: [4096,1024] x [1024,3072] -> [4096,3072]
    gemm_bt<1, 1><<<dim3(3072 / 128, 4096 / 128), 256, 0, stream>>>(
        x, Wqkv, QKV, 4096, 3072, 1024, 1024, 3072);

    flash_kernel<<<dim3(16, 32), 256, 0, stream>>>(QKV);

    // output projection: A = O (bf16, Q region of QKV, lda=3072)
    gemm_bt<0, 0><<<dim3(1024 / 128, 4096 / 128), 256, 0, stream>>>(
        QKV, Wot, out, 4096, 1024, 1024, 3072, 1024);
}

// Round 4
// 161.919 us; speedup vs baseline: 2.2149x; 1.3986x over previous
//
#include <hip/hip_runtime.h>
#include <cstdint>
#include <cstddef>

// ---------- types ----------
typedef __attribute__((ext_vector_type(8))) __bf16 bf16x8;
typedef __attribute__((ext_vector_type(4))) float f32x4;

// fp32 -> bf16 round-to-nearest-even (manual; used where vector cvt isn't natural)
__device__ __forceinline__ unsigned short f2bf(float x) {
    unsigned int u = __float_as_uint(x);
    u += 0x7fffu + ((u >> 16) & 1u);
    return (unsigned short)(u >> 16);
}

typedef const __attribute__((address_space(1))) void* gptr_t;
typedef __attribute__((address_space(3))) void* lptr_t;
__device__ __forceinline__ void gload_lds16(const void* g, void* l) {
    __builtin_amdgcn_global_load_lds((gptr_t)g, (lptr_t)l, 16, 0, 0);
}

// ---------- fused tiled transpose+cast of the 4 weight matrices ----------
// Wt[n][k] = W[k][n] * scale ; D=1024, 64x64 tiles, grid (16,16,4)
__global__ __launch_bounds__(256) void transpose4_kernel(const float* __restrict__ W0,
                                                         const float* __restrict__ W1,
                                                         const float* __restrict__ W2,
                                                         const float* __restrict__ W3,
                                                         unsigned short* __restrict__ T0,
                                                         unsigned short* __restrict__ T1,
                                                         unsigned short* __restrict__ T2,
                                                         unsigned short* __restrict__ T3,
                                                         float s0) {
    __shared__ float Ts[64][65];
    const int D = 1024;
    const int m = blockIdx.z;
    const float* W = (m == 0) ? W0 : (m == 1) ? W1 : (m == 2) ? W2 : W3;
    unsigned short* T = (m == 0) ? T0 : (m == 1) ? T1 : (m == 2) ? T2 : T3;
    const float scale = (m == 0) ? s0 : 1.0f;
    const int kt = blockIdx.y * 64, nt = blockIdx.x * 64;
    const int tid = threadIdx.x;

    {   // read 64x64 f32 tile, coalesced (each thread: 64B along one row)
        const int r = tid >> 2, cs = (tid & 3) * 16;
#pragma unroll
        for (int j = 0; j < 16; j += 4) {
            f32x4 v = *(const f32x4*)&W[(size_t)(kt + r) * D + nt + cs + j];
#pragma unroll
            for (int e = 0; e < 4; ++e) Ts[r][cs + j + e] = v[e];
        }
    }
    __syncthreads();
    {   // write transposed bf16 rows, 32B contiguous per thread
        const int n = tid >> 2, ks = (tid & 3) * 16;
        union { bf16x8 v[2]; __bf16 e[16]; } cv;
#pragma unroll
        for (int j = 0; j < 16; ++j) cv.e[j] = (__bf16)(Ts[ks + j][n] * scale);
        *(bf16x8*)&T[(size_t)(nt + n) * D + kt + ks] = cv.v[0];
        *(bf16x8*)&T[(size_t)(nt + n) * D + kt + ks + 8] = cv.v[1];
    }
}

// ---------- GEMM, C = A * B with Bt = B^T given ----------
// A [M,K] row stride lda (fp32 reg-staged if AF32, else bf16 via global_load_lds),
// Bt [N,K] bf16 row-major (stride K), C [M,N] row stride ldc (bf16 if OUTBF else f32).
// 128x128 tile, BK=32, 4 waves, each wave 64x64 (4x4 fragments of 16x16x32)
template <int AF32, int OUTBF>
__global__ __launch_bounds__(256) void gemm_bt(const void* __restrict__ Ain,
                                               const unsigned short* __restrict__ Bt,
                                               void* __restrict__ Cout,
                                               int M, int N, int K, int lda, int ldc) {
    __shared__ __align__(16) unsigned short Au[128 * 32];
    __shared__ __align__(16) unsigned short Bs[128 * 32];
    const int tid = threadIdx.x;
    const int w = tid >> 6;
    const int lane = tid & 63;
    const int m0 = blockIdx.y * 128;
    const int n0 = blockIdx.x * 128;
    const int wr = w >> 1, wc = w & 1;

    f32x4 acc[4][4];
#pragma unroll
    for (int i = 0; i < 4; ++i)
#pragma unroll
        for (int j = 0; j < 4; ++j) acc[i][j] = f32x4{0.f, 0.f, 0.f, 0.f};

    // AF32 staging geometry: thread covers A row (tid>>1), 16 f32 at col (tid&1)*16
    const int arow = tid >> 1;
    const int akh = tid & 1;
    const float* A32 = (const float*)Ain;
    f32x4 ar[4];
    if (AF32) {
        const float* s = A32 + (size_t)(m0 + arow) * lda + akh * 16;
#pragma unroll
        for (int j = 0; j < 4; ++j) ar[j] = *(const f32x4*)(s + j * 4);
    }

    for (int kt = 0; kt < K; kt += 32) {
        // ---- stage A tile ----
        if (AF32) {
            union { bf16x8 v[2]; __bf16 e[16]; } cv;
#pragma unroll
            for (int j = 0; j < 16; ++j) cv.e[j] = (__bf16)ar[j >> 2][j & 3];
            *(bf16x8*)&Au[arow * 32 + akh * 16] = cv.v[0];
            *(bf16x8*)&Au[arow * 32 + akh * 16 + 8] = cv.v[1];
        } else {
            const unsigned short* A = (const unsigned short*)Ain;
#pragma unroll
            for (int p = 0; p < 2; ++p) {
                int c = p * 4 + w;
                int row = c * 16 + (lane >> 2);
                gload_lds16(A + (size_t)(m0 + row) * lda + kt + (lane & 3) * 8,
                            &Au[c * 512]);
            }
        }
        // ---- stage Bt tile (bf16, row-major [128][32]) ----
#pragma unroll
        for (int p = 0; p < 2; ++p) {
            int c = p * 4 + w;
            int row = c * 16 + (lane >> 2);
            gload_lds16(Bt + (size_t)(n0 + row) * K + kt + (lane & 3) * 8,
                        &Bs[c * 512]);
        }
        __syncthreads();

        // ---- prefetch next A tile into registers (latency hides under MFMA) ----
        if (AF32 && kt + 32 < K) {
            const float* s = A32 + (size_t)(m0 + arow) * lda + kt + 32 + akh * 16;
#pragma unroll
            for (int j = 0; j < 4; ++j) ar[j] = *(const f32x4*)(s + j * 4);
        }

        // ---- fragments + MFMA ----
        bf16x8 af[4], bfr[4];
#pragma unroll
        for (int m = 0; m < 4; ++m)
            af[m] = *(const bf16x8*)&Au[(wr * 64 + m * 16 + (lane & 15)) * 32 +
                                        (lane >> 4) * 8];
#pragma unroll
        for (int n = 0; n < 4; ++n)
            bfr[n] = *(const bf16x8*)&Bs[(wc * 64 + n * 16 + (lane & 15)) * 32 +
                                         (lane >> 4) * 8];
#pragma unroll
        for (int m = 0; m < 4; ++m)
#pragma unroll
            for (int n = 0; n < 4; ++n)
                acc[m][n] = __builtin_amdgcn_mfma_f32_16x16x32_bf16(af[m], bfr[n], acc[m][n], 0, 0, 0);
        __syncthreads();
    }

    const int crow = (lane >> 4) * 4;
    const int ccol = lane & 15;
#pragma unroll
    for (int m = 0; m < 4; ++m) {
#pragma unroll
        for (int n = 0; n < 4; ++n) {
            int r0 = m0 + wr * 64 + m * 16 + crow;
            int c0 = n0 + wc * 64 + n * 16 + ccol;
#pragma unroll
            for (int j = 0; j < 4; ++j) {
                if (OUTBF)
                    ((unsigned short*)Cout)[(size_t)(r0 + j) * ldc + c0] = f2bf(acc[m][n][j]);
                else
                    ((float*)Cout)[(size_t)(r0 + j) * ldc + c0] = acc[m][n][j];
            }
        }
    }
}

// ---------- causal flash attention ----------
// QKV fused [B*L, 3072] bf16: Q cols [0,1024), K cols [1024,2048), V cols [2048,3072).
// Q is pre-scaled by 1/sqrt(hd) (folded into Wq).
// O written in-place over the Q columns (each block reads only its own Q rows,
// before writing them; K/V columns never overlap O).
// Grid (16, 32): block x=i processes qblk i then 31-i -> constant 33 KV tiles.
__global__ __launch_bounds__(256) void flash_kernel(unsigned short* __restrict__ QKV) {
    __shared__ __align__(16) unsigned short Ks[64 * 72];      // [kv][d], +8 pad
    __shared__ __align__(16) unsigned short Vs[64 * 72];      // [d][kv], kv XOR-swizzled
    __shared__ __align__(16) unsigned short Ps[4][16 * 72];   // per-wave P tile

    const int tid = threadIdx.x;
    const int w = tid >> 6;
    const int lane = tid & 63;
    const int bh = blockIdx.y;          // 0..31
    const int b = bh >> 4, h = bh & 15;
    const int rowbase = b * 2048;
    const int hd0 = h * 64;
    const int S = 3072;

    // staging indices: thread covers K rows {p*32+sr}, cols [sc, sc+8)
    const int sr = tid >> 3;            // 0..31
    const int sc = (tid & 7) * 8;       // 0..56
    const int vswz = (tid & 7) << 3;    // V store column swizzle = (d>>3)&7 for d in [sc,sc+8)

    for (int phase = 0; phase < 2; ++phase) {
        const int qblk = (phase == 0 ? (int)blockIdx.x : 31 - (int)blockIdx.x) * 64;
        const int q0 = qblk + w * 16;
        const int nt = qblk / 64 + 1;

        // Q fragments (A-operand), 2 k-steps of 32 over hd=64
        bf16x8 qf[2];
#pragma unroll
        for (int st = 0; st < 2; ++st)
            qf[st] = *(const bf16x8*)(QKV + (size_t)(rowbase + q0 + (lane & 15)) * S + hd0 +
                                      st * 32 + (lane >> 4) * 8);

        float m_prev[4], lsum[4];
        f32x4 oacc[4];
#pragma unroll
        for (int j = 0; j < 4; ++j) { m_prev[j] = -1e30f; lsum[j] = 0.f; }
#pragma unroll
        for (int n = 0; n < 4; ++n) oacc[n] = f32x4{0.f, 0.f, 0.f, 0.f};

        // prologue: load KV tile 0 into registers
        bf16x8 kreg[2], vreg[2];
#pragma unroll
        for (int p = 0; p < 2; ++p) {
            size_t gi = (size_t)(rowbase + p * 32 + sr) * S + hd0 + sc;
            kreg[p] = *(const bf16x8*)(QKV + gi + 1024);
            vreg[p] = *(const bf16x8*)(QKV + gi + 2048);
        }

        for (int t = 0; t < nt; ++t) {
            __syncthreads();   // all waves done reading LDS of previous tile
            // ---- write staged regs to LDS ----
#pragma unroll
            for (int p = 0; p < 2; ++p) {
                int r = p * 32 + sr;
                *(bf16x8*)&Ks[r * 72 + sc] = kreg[p];
                int rs = r ^ vswz;
#pragma unroll
                for (int jj = 0; jj < 8; ++jj)
                    Vs[(sc + jj) * 72 + rs] = ((const unsigned short*)&vreg[p])[jj];
            }
            __syncthreads();
            // ---- issue next tile's global loads (latency hidden under compute) ----
            if (t + 1 < nt) {
#pragma unroll
                for (int p = 0; p < 2; ++p) {
                    size_t gi = (size_t)(rowbase + (t + 1) * 64 + p * 32 + sr) * S + hd0 + sc;
                    kreg[p] = *(const bf16x8*)(QKV + gi + 1024);
                    vreg[p] = *(const bf16x8*)(QKV + gi + 2048);
                }
            }

            // ---- S = Q K^T (16 x 64) ----
            f32x4 sacc[4];
#pragma unroll
            for (int n = 0; n < 4; ++n) {
                bf16x8 k0 = *(const bf16x8*)&Ks[(n * 16 + (lane & 15)) * 72 + (lane >> 4) * 8];
                bf16x8 k1 = *(const bf16x8*)&Ks[(n * 16 + (lane & 15)) * 72 + 32 + (lane >> 4) * 8];
                f32x4 c = f32x4{0.f, 0.f, 0.f, 0.f};
                c = __builtin_amdgcn_mfma_f32_16x16x32_bf16(qf[0], k0, c, 0, 0, 0);
                c = __builtin_amdgcn_mfma_f32_16x16x32_bf16(qf[1], k1, c, 0, 0, 0);
                sacc[n] = c;
            }

            // ---- online softmax (per row j); mask only on the diagonal tile ----
            const bool diag = (t == nt - 1);
#pragma unroll
            for (int j = 0; j < 4; ++j) {
                int rr = w * 16 + (lane >> 4) * 4 + j;   // row - qblk
                float sv[4];
                float tmax = -1e30f;
#pragma unroll
                for (int n = 0; n < 4; ++n) {
                    float v = sacc[n][j];
                    if (diag) {
                        int cc = n * 16 + (lane & 15);   // col - kv0
                        if (cc > rr) v = -1e30f;
                    }
                    sv[n] = v;
                    tmax = fmaxf(tmax, v);
                }
#pragma unroll
                for (int off = 8; off >= 1; off >>= 1)
                    tmax = fmaxf(tmax, __shfl_xor(tmax, off, 16));
                float mnew = fmaxf(m_prev[j], tmax);
                float alpha = __expf(m_prev[j] - mnew);
                float psum = 0.f;
#pragma unroll
                for (int n = 0; n < 4; ++n) {
                    float p = __expf(sv[n] - mnew);
                    psum += p;
                    Ps[w][((lane >> 4) * 4 + j) * 72 + n * 16 + (lane & 15)] = f2bf(p);
                }
#pragma unroll
                for (int off = 8; off >= 1; off >>= 1)
                    psum += __shfl_xor(psum, off, 16);
                lsum[j] = lsum[j] * alpha + psum;
                m_prev[j] = mnew;
#pragma unroll
                for (int n = 0; n < 4; ++n) oacc[n][j] *= alpha;
            }

            // compile-time fence: Ps writes must precede the reads below
            asm volatile("" ::: "memory");

            // ---- O += P V ---- (DS ops complete in-order within a wave)
#pragma unroll
            for (int st = 0; st < 2; ++st) {
                bf16x8 pa = *(const bf16x8*)&Ps[w][(lane & 15) * 72 + st * 32 + (lane >> 4) * 8];
#pragma unroll
                for (int n = 0; n < 4; ++n) {
                    int d = n * 16 + (lane & 15);
                    int o = (st * 32 + (lane >> 4) * 8) ^ (((d >> 3) & 7) << 3);
                    bf16x8 vfr = *(const bf16x8*)&Vs[d * 72 + o];
                    oacc[n] = __builtin_amdgcn_mfma_f32_16x16x32_bf16(pa, vfr, oacc[n], 0, 0, 0);
                }
            }
        }

        // ---- normalize and write O over this block's own Q rows ----
#pragma unroll
        for (int n = 0; n < 4; ++n) {
#pragma unroll
            for (int j = 0; j < 4; ++j) {
                int row = q0 + (lane >> 4) * 4 + j;
                int col = hd0 + n * 16 + (lane & 15);
                QKV[(size_t)(rowbase + row) * S + col] = f2bf(oacc[n][j] / lsum[j]);
            }
        }
        __syncthreads();   // phase isolation for LDS reuse
    }
}

// ---------- launch ----------
extern "C" void kernel_launch(void* const* d_in, const int* in_sizes, int n_in,
                              void* d_out, int out_size, void* d_ws, size_t ws_size,
                              hipStream_t stream) {
    const float* x  = (const float*)d_in[0];
    const float* Wq = (const float*)d_in[1];
    const float* Wk = (const float*)d_in[2];
    const float* Wv = (const float*)d_in[3];
    const float* Wo = (const float*)d_in[4];
    float* out = (float*)d_out;

    const int WN = 1024 * 1024;

    // workspace: Wqkv_t [3072][1024] (6MB) + Wo_t (2MB) + QKV [4096][3072] (24MB) = 32MB
    unsigned short* ws   = (unsigned short*)d_ws;
    unsigned short* Wqkv = ws;                 // rows 0..1023 Wq^T*scale, 1024.. Wk^T, 2048.. Wv^T
    unsigned short* Wot  = Wqkv + 3 * WN;
    unsigned short* QKV  = Wot + WN;

    transpose4_kernel<<<dim3(16, 16, 4), 256, 0, stream>>>(
        Wq, Wk, Wv, Wo, Wqkv, Wqkv + WN, Wqkv + 2 * WN, Wot, 0.125f);

    // fused QKV projection: [4096,1024] x [1024,3072] -> [4096,3072]
    gemm_bt<1, 1><<<dim3(3072 / 128, 4096 / 128), 256, 0, stream>>>(
        x, Wqkv, QKV, 4096, 3072, 1024, 1024, 3072);

    flash_kernel<<<dim3(16, 32), 256, 0, stream>>>(QKV);

    // output projection: A = O (bf16, Q region of QKV, lda=3072)
    gemm_bt<0, 0><<<dim3(1024 / 128, 4096 / 128), 256, 0, stream>>>(
        QKV, Wot, out, 4096, 1024, 1024, 3072, 1024);
}

// Round 5
// 150.815 us; speedup vs baseline: 2.3780x; 1.0736x over previous
//
#include <hip/hip_runtime.h>
#include <cstdint>
#include <cstddef>

// ---------- types ----------
typedef __attribute__((ext_vector_type(8))) __bf16 bf16x8;
typedef __attribute__((ext_vector_type(4))) float f32x4;

// fp32 -> bf16 round-to-nearest-even (manual; used where vector cvt isn't natural)
__device__ __forceinline__ unsigned short f2bf(float x) {
    unsigned int u = __float_as_uint(x);
    u += 0x7fffu + ((u >> 16) & 1u);
    return (unsigned short)(u >> 16);
}

typedef const __attribute__((address_space(1))) void* gptr_t;
typedef __attribute__((address_space(3))) void* lptr_t;
__device__ __forceinline__ void gload_lds16(const void* g, void* l) {
    __builtin_amdgcn_global_load_lds((gptr_t)g, (lptr_t)l, 16, 0, 0);
}

// ---------- fused tiled transpose+cast of the 4 weight matrices ----------
// Wt[n][k] = W[k][n] * scale ; D=1024, 64x64 tiles, grid (16,16,4)
__global__ __launch_bounds__(256) void transpose4_kernel(const float* __restrict__ W0,
                                                         const float* __restrict__ W1,
                                                         const float* __restrict__ W2,
                                                         const float* __restrict__ W3,
                                                         unsigned short* __restrict__ T0,
                                                         unsigned short* __restrict__ T1,
                                                         unsigned short* __restrict__ T2,
                                                         unsigned short* __restrict__ T3,
                                                         float s0) {
    __shared__ float Ts[64][65];
    const int D = 1024;
    const int m = blockIdx.z;
    const float* W = (m == 0) ? W0 : (m == 1) ? W1 : (m == 2) ? W2 : W3;
    unsigned short* T = (m == 0) ? T0 : (m == 1) ? T1 : (m == 2) ? T2 : T3;
    const float scale = (m == 0) ? s0 : 1.0f;
    const int kt = blockIdx.y * 64, nt = blockIdx.x * 64;
    const int tid = threadIdx.x;

    {   // read 64x64 f32 tile, coalesced (each thread: 64B along one row)
        const int r = tid >> 2, cs = (tid & 3) * 16;
#pragma unroll
        for (int j = 0; j < 16; j += 4) {
            f32x4 v = *(const f32x4*)&W[(size_t)(kt + r) * D + nt + cs + j];
#pragma unroll
            for (int e = 0; e < 4; ++e) Ts[r][cs + j + e] = v[e];
        }
    }
    __syncthreads();
    {   // write transposed bf16 rows, 32B contiguous per thread
        const int n = tid >> 2, ks = (tid & 3) * 16;
        union { bf16x8 v[2]; __bf16 e[16]; } cv;
#pragma unroll
        for (int j = 0; j < 16; ++j) cv.e[j] = (__bf16)(Ts[ks + j][n] * scale);
        *(bf16x8*)&T[(size_t)(nt + n) * D + kt + ks] = cv.v[0];
        *(bf16x8*)&T[(size_t)(nt + n) * D + kt + ks + 8] = cv.v[1];
    }
}

// ---------- GEMM, C = A * B with Bt = B^T given ----------
// A [M,K] row stride lda (fp32 reg-staged if AF32, else bf16 via global_load_lds),
// Bt [N,K] bf16 row-major (stride K), C [M,N] row stride ldc (bf16 if OUTBF else f32).
// 128x128 tile, BK=32, 4 waves, each wave 64x64 (4x4 fragments of 16x16x32).
// 1D grid, bijective XCD-chunk swizzle (requires gridDim.x % 8 == 0): each XCD
// owns a contiguous chunk of M-panels -> A panels fetched once per XCD L2.
template <int AF32, int OUTBF>
__global__ __launch_bounds__(256) void gemm_bt(const void* __restrict__ Ain,
                                               const unsigned short* __restrict__ Bt,
                                               void* __restrict__ Cout,
                                               int M, int N, int K, int lda, int ldc,
                                               int nbx) {
    __shared__ __align__(16) unsigned short Au[128 * 32];
    __shared__ __align__(16) unsigned short Bs[128 * 32];
    const int tid = threadIdx.x;
    const int w = tid >> 6;
    const int lane = tid & 63;

    // XCD-aware bijective swizzle: orig%8 = XCD (round-robin dispatch); give
    // each XCD a contiguous newlin range; decompose by-major so the range
    // spans few M-panels (A reuse within the XCD's L2).
    const int nwg = gridDim.x;
    const int q8 = nwg >> 3;
    const int orig = blockIdx.x;
    const int newlin = (orig & 7) * q8 + (orig >> 3);
    const int by = newlin / nbx;
    const int bx = newlin - by * nbx;
    const int m0 = by * 128;
    const int n0 = bx * 128;
    const int wr = w >> 1, wc = w & 1;

    f32x4 acc[4][4];
#pragma unroll
    for (int i = 0; i < 4; ++i)
#pragma unroll
        for (int j = 0; j < 4; ++j) acc[i][j] = f32x4{0.f, 0.f, 0.f, 0.f};

    // AF32 staging geometry: thread covers A row (tid>>1), 16 f32 at col (tid&1)*16
    const int arow = tid >> 1;
    const int akh = tid & 1;
    const float* A32 = (const float*)Ain;
    f32x4 ar[4];
    if (AF32) {
        const float* s = A32 + (size_t)(m0 + arow) * lda + akh * 16;
#pragma unroll
        for (int j = 0; j < 4; ++j) ar[j] = *(const f32x4*)(s + j * 4);
    }

    for (int kt = 0; kt < K; kt += 32) {
        // ---- stage A tile ----
        if (AF32) {
            union { bf16x8 v[2]; __bf16 e[16]; } cv;
#pragma unroll
            for (int j = 0; j < 16; ++j) cv.e[j] = (__bf16)ar[j >> 2][j & 3];
            *(bf16x8*)&Au[arow * 32 + akh * 16] = cv.v[0];
            *(bf16x8*)&Au[arow * 32 + akh * 16 + 8] = cv.v[1];
        } else {
            const unsigned short* A = (const unsigned short*)Ain;
#pragma unroll
            for (int p = 0; p < 2; ++p) {
                int c = p * 4 + w;
                int row = c * 16 + (lane >> 2);
                gload_lds16(A + (size_t)(m0 + row) * lda + kt + (lane & 3) * 8,
                            &Au[c * 512]);
            }
        }
        // ---- stage Bt tile (bf16, row-major [128][32]) ----
#pragma unroll
        for (int p = 0; p < 2; ++p) {
            int c = p * 4 + w;
            int row = c * 16 + (lane >> 2);
            gload_lds16(Bt + (size_t)(n0 + row) * K + kt + (lane & 3) * 8,
                        &Bs[c * 512]);
        }
        __syncthreads();

        // ---- prefetch next A tile into registers (latency hides under MFMA) ----
        if (AF32 && kt + 32 < K) {
            const float* s = A32 + (size_t)(m0 + arow) * lda + kt + 32 + akh * 16;
#pragma unroll
            for (int j = 0; j < 4; ++j) ar[j] = *(const f32x4*)(s + j * 4);
        }

        // ---- fragments + MFMA ----
        bf16x8 af[4], bfr[4];
#pragma unroll
        for (int m = 0; m < 4; ++m)
            af[m] = *(const bf16x8*)&Au[(wr * 64 + m * 16 + (lane & 15)) * 32 +
                                        (lane >> 4) * 8];
#pragma unroll
        for (int n = 0; n < 4; ++n)
            bfr[n] = *(const bf16x8*)&Bs[(wc * 64 + n * 16 + (lane & 15)) * 32 +
                                         (lane >> 4) * 8];
#pragma unroll
        for (int m = 0; m < 4; ++m)
#pragma unroll
            for (int n = 0; n < 4; ++n)
                acc[m][n] = __builtin_amdgcn_mfma_f32_16x16x32_bf16(af[m], bfr[n], acc[m][n], 0, 0, 0);
        __syncthreads();
    }

    const int crow = (lane >> 4) * 4;
    const int ccol = lane & 15;
#pragma unroll
    for (int m = 0; m < 4; ++m) {
#pragma unroll
        for (int n = 0; n < 4; ++n) {
            int r0 = m0 + wr * 64 + m * 16 + crow;
            int c0 = n0 + wc * 64 + n * 16 + ccol;
#pragma unroll
            for (int j = 0; j < 4; ++j) {
                if (OUTBF)
                    ((unsigned short*)Cout)[(size_t)(r0 + j) * ldc + c0] = f2bf(acc[m][n][j]);
                else
                    ((float*)Cout)[(size_t)(r0 + j) * ldc + c0] = acc[m][n][j];
            }
        }
    }
}

// ---------- causal flash attention ----------
// QKV fused [B*L, 3072] bf16: Q cols [0,1024), K cols [1024,2048), V cols [2048,3072).
// Q pre-scaled by 1/sqrt(hd) (folded into Wq). O written in-place over Q columns.
// Grid (32 bh, 16 pair): linear%8 = bh%8 -> all 16 blocks of one head share an
// XCD (K/V panel cached once per L2). Block y=i processes qblk i then 31-i
// (constant 33 KV tiles). Double-buffered K/V LDS, ONE barrier per tile:
//   iter t: write regs(t+1)->buf[cur^1]; issue loads(t+2); compute buf[cur]; barrier.
// Safety: buf[cur^1] was last READ in iter t-1 (barrier t-1 orders it before
// our write); buf[cur^1] writes complete before barrier t, read in iter t+1.
__global__ __launch_bounds__(256) void flash_kernel(unsigned short* __restrict__ QKV) {
    __shared__ __align__(16) unsigned short Ks[2][64 * 72];   // [kv][d], +8 pad
    __shared__ __align__(16) unsigned short Vs[2][64 * 72];   // [d][kv], kv XOR-swizzled
    __shared__ __align__(16) unsigned short Ps[4][16 * 72];   // per-wave P tile

    const int tid = threadIdx.x;
    const int w = tid >> 6;
    const int lane = tid & 63;
    const int bh = blockIdx.x;          // 0..31 ; XCD = bh % 8
    const int b = bh >> 4, h = bh & 15;
    const int rowbase = b * 2048;
    const int hd0 = h * 64;
    const int S = 3072;

    // staging indices: thread covers K rows {p*32+sr}, cols [sc, sc+8)
    const int sr = tid >> 3;            // 0..31
    const int sc = (tid & 7) * 8;       // 0..56
    const int vswz = (tid & 7) << 3;    // V store column swizzle

    for (int phase = 0; phase < 2; ++phase) {
        const int qblk = (phase == 0 ? (int)blockIdx.y : 31 - (int)blockIdx.y) * 64;
        const int q0 = qblk + w * 16;
        const int nt = qblk / 64 + 1;

        // Q fragments (A-operand), 2 k-steps of 32 over hd=64
        bf16x8 qf[2];
#pragma unroll
        for (int st = 0; st < 2; ++st)
            qf[st] = *(const bf16x8*)(QKV + (size_t)(rowbase + q0 + (lane & 15)) * S + hd0 +
                                      st * 32 + (lane >> 4) * 8);

        float m_prev[4], lsum[4];
        f32x4 oacc[4];
#pragma unroll
        for (int j = 0; j < 4; ++j) { m_prev[j] = -1e30f; lsum[j] = 0.f; }
#pragma unroll
        for (int n = 0; n < 4; ++n) oacc[n] = f32x4{0.f, 0.f, 0.f, 0.f};

        bf16x8 kreg[2], vreg[2];
        // prologue: tile 0 -> regs -> buf0 ; tile 1 -> regs
#pragma unroll
        for (int p = 0; p < 2; ++p) {
            size_t gi = (size_t)(rowbase + p * 32 + sr) * S + hd0 + sc;
            kreg[p] = *(const bf16x8*)(QKV + gi + 1024);
            vreg[p] = *(const bf16x8*)(QKV + gi + 2048);
        }
#pragma unroll
        for (int p = 0; p < 2; ++p) {
            int r = p * 32 + sr;
            *(bf16x8*)&Ks[0][r * 72 + sc] = kreg[p];
            int rs = r ^ vswz;
#pragma unroll
            for (int jj = 0; jj < 8; ++jj)
                Vs[0][(sc + jj) * 72 + rs] = ((const unsigned short*)&vreg[p])[jj];
        }
        if (nt > 1) {
#pragma unroll
            for (int p = 0; p < 2; ++p) {
                size_t gi = (size_t)(rowbase + 64 + p * 32 + sr) * S + hd0 + sc;
                kreg[p] = *(const bf16x8*)(QKV + gi + 1024);
                vreg[p] = *(const bf16x8*)(QKV + gi + 2048);
            }
        }
        __syncthreads();

        int cur = 0;
        for (int t = 0; t < nt; ++t) {
            // ---- write staged regs (tile t+1) to the other buffer ----
            if (t + 1 < nt) {
#pragma unroll
                for (int p = 0; p < 2; ++p) {
                    int r = p * 32 + sr;
                    *(bf16x8*)&Ks[cur ^ 1][r * 72 + sc] = kreg[p];
                    int rs = r ^ vswz;
#pragma unroll
                    for (int jj = 0; jj < 8; ++jj)
                        Vs[cur ^ 1][(sc + jj) * 72 + rs] = ((const unsigned short*)&vreg[p])[jj];
                }
                // ---- issue tile t+2 global loads ----
                if (t + 2 < nt) {
#pragma unroll
                    for (int p = 0; p < 2; ++p) {
                        size_t gi = (size_t)(rowbase + (t + 2) * 64 + p * 32 + sr) * S + hd0 + sc;
                        kreg[p] = *(const bf16x8*)(QKV + gi + 1024);
                        vreg[p] = *(const bf16x8*)(QKV + gi + 2048);
                    }
                }
            }

            // ---- S = Q K^T (16 x 64) from buf[cur] ----
            const unsigned short* Kc = Ks[cur];
            const unsigned short* Vc = Vs[cur];
            f32x4 sacc[4];
#pragma unroll
            for (int n = 0; n < 4; ++n) {
                bf16x8 k0 = *(const bf16x8*)&Kc[(n * 16 + (lane & 15)) * 72 + (lane >> 4) * 8];
                bf16x8 k1 = *(const bf16x8*)&Kc[(n * 16 + (lane & 15)) * 72 + 32 + (lane >> 4) * 8];
                f32x4 c = f32x4{0.f, 0.f, 0.f, 0.f};
                c = __builtin_amdgcn_mfma_f32_16x16x32_bf16(qf[0], k0, c, 0, 0, 0);
                c = __builtin_amdgcn_mfma_f32_16x16x32_bf16(qf[1], k1, c, 0, 0, 0);
                sacc[n] = c;
            }

            // ---- online softmax (per row j); mask only on the diagonal tile ----
            const bool diag = (t == nt - 1);
#pragma unroll
            for (int j = 0; j < 4; ++j) {
                int rr = w * 16 + (lane >> 4) * 4 + j;   // row - qblk
                float sv[4];
                float tmax = -1e30f;
#pragma unroll
                for (int n = 0; n < 4; ++n) {
                    float v = sacc[n][j];
                    if (diag) {
                        int cc = n * 16 + (lane & 15);   // col - kv0
                        if (cc > rr) v = -1e30f;
                    }
                    sv[n] = v;
                    tmax = fmaxf(tmax, v);
                }
#pragma unroll
                for (int off = 8; off >= 1; off >>= 1)
                    tmax = fmaxf(tmax, __shfl_xor(tmax, off, 16));
                float mnew = fmaxf(m_prev[j], tmax);
                float alpha = __expf(m_prev[j] - mnew);
                float psum = 0.f;
#pragma unroll
                for (int n = 0; n < 4; ++n) {
                    float p = __expf(sv[n] - mnew);
                    psum += p;
                    Ps[w][((lane >> 4) * 4 + j) * 72 + n * 16 + (lane & 15)] = f2bf(p);
                }
#pragma unroll
                for (int off = 8; off >= 1; off >>= 1)
                    psum += __shfl_xor(psum, off, 16);
                lsum[j] = lsum[j] * alpha + psum;
                m_prev[j] = mnew;
#pragma unroll
                for (int n = 0; n < 4; ++n) oacc[n][j] *= alpha;
            }

            // compile-time fence: Ps writes must precede the reads below
            asm volatile("" ::: "memory");

            // ---- O += P V ---- (DS ops complete in-order within a wave)
#pragma unroll
            for (int st = 0; st < 2; ++st) {
                bf16x8 pa = *(const bf16x8*)&Ps[w][(lane & 15) * 72 + st * 32 + (lane >> 4) * 8];
#pragma unroll
                for (int n = 0; n < 4; ++n) {
                    int d = n * 16 + (lane & 15);
                    int o = (st * 32 + (lane >> 4) * 8) ^ (((d >> 3) & 7) << 3);
                    bf16x8 vfr = *(const bf16x8*)&Vc[d * 72 + o];
                    oacc[n] = __builtin_amdgcn_mfma_f32_16x16x32_bf16(pa, vfr, oacc[n], 0, 0, 0);
                }
            }
            __syncthreads();
            cur ^= 1;
        }

        // ---- normalize and write O over this block's own Q rows ----
#pragma unroll
        for (int n = 0; n < 4; ++n) {
#pragma unroll
            for (int j = 0; j < 4; ++j) {
                int row = q0 + (lane >> 4) * 4 + j;
                int col = hd0 + n * 16 + (lane & 15);
                QKV[(size_t)(rowbase + row) * S + col] = f2bf(oacc[n][j] / lsum[j]);
            }
        }
    }
}

// ---------- launch ----------
extern "C" void kernel_launch(void* const* d_in, const int* in_sizes, int n_in,
                              void* d_out, int out_size, void* d_ws, size_t ws_size,
                              hipStream_t stream) {
    const float* x  = (const float*)d_in[0];
    const float* Wq = (const float*)d_in[1];
    const float* Wk = (const float*)d_in[2];
    const float* Wv = (const float*)d_in[3];
    const float* Wo = (const float*)d_in[4];
    float* out = (float*)d_out;

    const int WN = 1024 * 1024;

    // workspace: Wqkv_t [3072][1024] (6MB) + Wo_t (2MB) + QKV [4096][3072] (24MB) = 32MB
    unsigned short* ws   = (unsigned short*)d_ws;
    unsigned short* Wqkv = ws;                 // rows 0..1023 Wq^T*scale, 1024.. Wk^T, 2048.. Wv^T
    unsigned short* Wot  = Wqkv + 3 * WN;
    unsigned short* QKV  = Wot + WN;

    transpose4_kernel<<<dim3(16, 16, 4), 256, 0, stream>>>(
        Wq, Wk, Wv, Wo, Wqkv, Wqkv + WN, Wqkv + 2 * WN, Wot, 0.125f);

    // fused QKV projection: [4096,1024] x [1024,3072] -> [4096,3072]
    gemm_bt<1, 1><<<24 * 32, 256, 0, stream>>>(
        x, Wqkv, QKV, 4096, 3072, 1024, 1024, 3072, 24);

    flash_kernel<<<dim3(32, 16), 256, 0, stream>>>(QKV);

    // output projection: A = O (bf16, Q region of QKV, lda=3072)
    gemm_bt<0, 0><<<8 * 32, 256, 0, stream>>>(
        QKV, Wot, out, 4096, 1024, 1024, 3072, 1024, 8);
}

// Round 6
// 137.127 us; speedup vs baseline: 2.6154x; 1.0998x over previous
//
#include <hip/hip_runtime.h>
#include <cstdint>
#include <cstddef>

// ---------- types ----------
typedef __attribute__((ext_vector_type(8))) __bf16 bf16x8;
typedef __attribute__((ext_vector_type(4))) float f32x4;

// fp32 -> bf16 round-to-nearest-even (manual; used where vector cvt isn't natural)
__device__ __forceinline__ unsigned short f2bf(float x) {
    unsigned int u = __float_as_uint(x);
    u += 0x7fffu + ((u >> 16) & 1u);
    return (unsigned short)(u >> 16);
}

__device__ __forceinline__ ushort4 pack4bf(float a, float b, float c, float d) {
    union { ushort4 v; __bf16 e[4]; } u;
    u.e[0] = (__bf16)a; u.e[1] = (__bf16)b; u.e[2] = (__bf16)c; u.e[3] = (__bf16)d;
    return u.v;
}

typedef const __attribute__((address_space(1))) void* gptr_t;
typedef __attribute__((address_space(3))) void* lptr_t;
__device__ __forceinline__ void gload_lds16(const void* g, void* l) {
    __builtin_amdgcn_global_load_lds((gptr_t)g, (lptr_t)l, 16, 0, 0);
}

// ---------- fused tiled transpose+cast of the 4 weight matrices ----------
// Wt[n][k] = W[k][n] * scale ; D=1024, 64x64 tiles, grid (16,16,4)
__global__ __launch_bounds__(256) void transpose4_kernel(const float* __restrict__ W0,
                                                         const float* __restrict__ W1,
                                                         const float* __restrict__ W2,
                                                         const float* __restrict__ W3,
                                                         unsigned short* __restrict__ T0,
                                                         unsigned short* __restrict__ T1,
                                                         unsigned short* __restrict__ T2,
                                                         unsigned short* __restrict__ T3,
                                                         float s0) {
    __shared__ float Ts[64][65];
    const int D = 1024;
    const int m = blockIdx.z;
    const float* W = (m == 0) ? W0 : (m == 1) ? W1 : (m == 2) ? W2 : W3;
    unsigned short* T = (m == 0) ? T0 : (m == 1) ? T1 : (m == 2) ? T2 : T3;
    const float scale = (m == 0) ? s0 : 1.0f;
    const int kt = blockIdx.y * 64, nt = blockIdx.x * 64;
    const int tid = threadIdx.x;

    {   // read 64x64 f32 tile, coalesced (each thread: 64B along one row)
        const int r = tid >> 2, cs = (tid & 3) * 16;
#pragma unroll
        for (int j = 0; j < 16; j += 4) {
            f32x4 v = *(const f32x4*)&W[(size_t)(kt + r) * D + nt + cs + j];
#pragma unroll
            for (int e = 0; e < 4; ++e) Ts[r][cs + j + e] = v[e];
        }
    }
    __syncthreads();
    {   // write transposed bf16 rows, 32B contiguous per thread
        const int n = tid >> 2, ks = (tid & 3) * 16;
        union { bf16x8 v[2]; __bf16 e[16]; } cv;
#pragma unroll
        for (int j = 0; j < 16; ++j) cv.e[j] = (__bf16)(Ts[ks + j][n] * scale);
        *(bf16x8*)&T[(size_t)(nt + n) * D + kt + ks] = cv.v[0];
        *(bf16x8*)&T[(size_t)(nt + n) * D + kt + ks + 8] = cv.v[1];
    }
}

// ---------- GEMM, C = A * B with Bt = B^T given ----------
// A [M,K] row stride lda (fp32 reg-staged if AF32, else bf16 via global_load_lds),
// Bt [N,K] bf16 row-major (stride K), C [M,N] row stride ldc (bf16 if OUTBF else f32).
// 128x128 tile, BK=32, 4 waves, each wave 64x64 (4x4 fragments of 16x16x32).
// 1D grid, bijective XCD-chunk swizzle (requires gridDim.x % 8 == 0).
template <int AF32, int OUTBF>
__global__ __launch_bounds__(256) void gemm_bt(const void* __restrict__ Ain,
                                               const unsigned short* __restrict__ Bt,
                                               void* __restrict__ Cout,
                                               int M, int N, int K, int lda, int ldc,
                                               int nbx) {
    __shared__ __align__(16) unsigned short Au[128 * 32];
    __shared__ __align__(16) unsigned short Bs[128 * 32];
    const int tid = threadIdx.x;
    const int w = tid >> 6;
    const int lane = tid & 63;

    const int nwg = gridDim.x;
    const int q8 = nwg >> 3;
    const int orig = blockIdx.x;
    const int newlin = (orig & 7) * q8 + (orig >> 3);
    const int by = newlin / nbx;
    const int bx = newlin - by * nbx;
    const int m0 = by * 128;
    const int n0 = bx * 128;
    const int wr = w >> 1, wc = w & 1;

    f32x4 acc[4][4];
#pragma unroll
    for (int i = 0; i < 4; ++i)
#pragma unroll
        for (int j = 0; j < 4; ++j) acc[i][j] = f32x4{0.f, 0.f, 0.f, 0.f};

    const int arow = tid >> 1;
    const int akh = tid & 1;
    const float* A32 = (const float*)Ain;
    f32x4 ar[4];
    if (AF32) {
        const float* s = A32 + (size_t)(m0 + arow) * lda + akh * 16;
#pragma unroll
        for (int j = 0; j < 4; ++j) ar[j] = *(const f32x4*)(s + j * 4);
    }

    for (int kt = 0; kt < K; kt += 32) {
        if (AF32) {
            union { bf16x8 v[2]; __bf16 e[16]; } cv;
#pragma unroll
            for (int j = 0; j < 16; ++j) cv.e[j] = (__bf16)ar[j >> 2][j & 3];
            *(bf16x8*)&Au[arow * 32 + akh * 16] = cv.v[0];
            *(bf16x8*)&Au[arow * 32 + akh * 16 + 8] = cv.v[1];
        } else {
            const unsigned short* A = (const unsigned short*)Ain;
#pragma unroll
            for (int p = 0; p < 2; ++p) {
                int c = p * 4 + w;
                int row = c * 16 + (lane >> 2);
                gload_lds16(A + (size_t)(m0 + row) * lda + kt + (lane & 3) * 8,
                            &Au[c * 512]);
            }
        }
#pragma unroll
        for (int p = 0; p < 2; ++p) {
            int c = p * 4 + w;
            int row = c * 16 + (lane >> 2);
            gload_lds16(Bt + (size_t)(n0 + row) * K + kt + (lane & 3) * 8,
                        &Bs[c * 512]);
        }
        __syncthreads();

        if (AF32 && kt + 32 < K) {
            const float* s = A32 + (size_t)(m0 + arow) * lda + kt + 32 + akh * 16;
#pragma unroll
            for (int j = 0; j < 4; ++j) ar[j] = *(const f32x4*)(s + j * 4);
        }

        bf16x8 af[4], bfr[4];
#pragma unroll
        for (int m = 0; m < 4; ++m)
            af[m] = *(const bf16x8*)&Au[(wr * 64 + m * 16 + (lane & 15)) * 32 +
                                        (lane >> 4) * 8];
#pragma unroll
        for (int n = 0; n < 4; ++n)
            bfr[n] = *(const bf16x8*)&Bs[(wc * 64 + n * 16 + (lane & 15)) * 32 +
                                         (lane >> 4) * 8];
#pragma unroll
        for (int m = 0; m < 4; ++m)
#pragma unroll
            for (int n = 0; n < 4; ++n)
                acc[m][n] = __builtin_amdgcn_mfma_f32_16x16x32_bf16(af[m], bfr[n], acc[m][n], 0, 0, 0);
        __syncthreads();
    }

    const int crow = (lane >> 4) * 4;
    const int ccol = lane & 15;
#pragma unroll
    for (int m = 0; m < 4; ++m) {
#pragma unroll
        for (int n = 0; n < 4; ++n) {
            int r0 = m0 + wr * 64 + m * 16 + crow;
            int c0 = n0 + wc * 64 + n * 16 + ccol;
#pragma unroll
            for (int j = 0; j < 4; ++j) {
                if (OUTBF)
                    ((unsigned short*)Cout)[(size_t)(r0 + j) * ldc + c0] = f2bf(acc[m][n][j]);
                else
                    ((float*)Cout)[(size_t)(r0 + j) * ldc + c0] = acc[m][n][j];
            }
        }
    }
}

// ---------- causal flash attention (swapped-operand, S^T/O^T in registers) ----------
// QKV fused [B*L, 3072] bf16: Q cols [0,1024), K [1024,2048), V [2048,3072).
// Q pre-scaled by log2(e)/sqrt(hd) (softmax runs in exp2 domain).
// O written in-place over Q columns (per-block row ownership).
// Grid (32 bh, 32 qblk): linear%8 = bh%8 -> one head's blocks share an XCD.
// y -> qblk 31-y: heavy blocks dispatch first. Per block: one 64-row qblk,
// 4 waves x 16 q. S^T = mfma(K,Q): lane holds S[kv=n*16+g*4+j][q=lane&15]
// -> softmax reductions are in-register + 2 shfl. PV: O^T = mfma(V^T, P^T).
__global__ __launch_bounds__(256) void flash_kernel(unsigned short* __restrict__ QKV) {
    __shared__ __align__(16) unsigned short Ks[2][64 * 72];   // [kv][d], +8 pad
    __shared__ __align__(16) unsigned short Vs[2][64 * 72];   // [d][kv], kv XOR-swizzled
    __shared__ __align__(16) unsigned short Ps[4][16 * 72];   // per-wave P^T as [q][kv^swz]

    const int tid = threadIdx.x;
    const int w = tid >> 6;
    const int lane = tid & 63;
    const int bh = blockIdx.x;          // 0..31 ; XCD = bh % 8
    const int b = bh >> 4, h = bh & 15;
    const int rowbase = b * 2048;
    const int hd0 = h * 64;
    const int S = 3072;

    const int sr = tid >> 3;            // staging: K rows {p*32+sr}
    const int sc = (tid & 7) * 8;       //          cols [sc, sc+8)
    const int vswz = (tid & 7) << 3;    // V store column swizzle

    const int qi = lane & 15;           // this lane's q column
    const int g = lane >> 4;            // lane group: kv sub-rows g*4..g*4+3
    const int pswz = (qi & 7) << 3;     // Ps kv-swizzle for row q

    const int qblk = (31 - (int)blockIdx.y) * 64;
    const int q0 = qblk + w * 16;
    const int nt = qblk / 64 + 1;
    const int q_rel = w * 16 + qi;      // q - qblk

    // Q fragments (B-operand), 2 d-steps of 32 over hd=64
    bf16x8 qf[2];
#pragma unroll
    for (int st = 0; st < 2; ++st)
        qf[st] = *(const bf16x8*)(QKV + (size_t)(rowbase + q0 + qi) * S + hd0 +
                                  st * 32 + g * 8);

    float m_prev = -1e30f, lsum = 0.f;
    f32x4 oacc[4];
#pragma unroll
    for (int n = 0; n < 4; ++n) oacc[n] = f32x4{0.f, 0.f, 0.f, 0.f};

    bf16x8 kreg[2], vreg[2];
    // prologue: tile 0 -> regs -> buf0 ; tile 1 -> regs
#pragma unroll
    for (int p = 0; p < 2; ++p) {
        size_t gi = (size_t)(rowbase + p * 32 + sr) * S + hd0 + sc;
        kreg[p] = *(const bf16x8*)(QKV + gi + 1024);
        vreg[p] = *(const bf16x8*)(QKV + gi + 2048);
    }
#pragma unroll
    for (int p = 0; p < 2; ++p) {
        int r = p * 32 + sr;
        *(bf16x8*)&Ks[0][r * 72 + sc] = kreg[p];
        int rs = r ^ vswz;
#pragma unroll
        for (int jj = 0; jj < 8; ++jj)
            Vs[0][(sc + jj) * 72 + rs] = ((const unsigned short*)&vreg[p])[jj];
    }
    if (nt > 1) {
#pragma unroll
        for (int p = 0; p < 2; ++p) {
            size_t gi = (size_t)(rowbase + 64 + p * 32 + sr) * S + hd0 + sc;
            kreg[p] = *(const bf16x8*)(QKV + gi + 1024);
            vreg[p] = *(const bf16x8*)(QKV + gi + 2048);
        }
    }
    __syncthreads();

    int cur = 0;
    for (int t = 0; t < nt; ++t) {
        // ---- write staged regs (tile t+1) to the other buffer; issue t+2 loads ----
        if (t + 1 < nt) {
#pragma unroll
            for (int p = 0; p < 2; ++p) {
                int r = p * 32 + sr;
                *(bf16x8*)&Ks[cur ^ 1][r * 72 + sc] = kreg[p];
                int rs = r ^ vswz;
#pragma unroll
                for (int jj = 0; jj < 8; ++jj)
                    Vs[cur ^ 1][(sc + jj) * 72 + rs] = ((const unsigned short*)&vreg[p])[jj];
            }
            if (t + 2 < nt) {
#pragma unroll
                for (int p = 0; p < 2; ++p) {
                    size_t gi = (size_t)(rowbase + (t + 2) * 64 + p * 32 + sr) * S + hd0 + sc;
                    kreg[p] = *(const bf16x8*)(QKV + gi + 1024);
                    vreg[p] = *(const bf16x8*)(QKV + gi + 2048);
                }
            }
        }

        const unsigned short* Kc = Ks[cur];
        const unsigned short* Vc = Vs[cur];

        // ---- S^T = K Q^T : sacc[n][j] = S[kv0 + n*16 + g*4 + j][q] ----
        f32x4 sacc[4];
        __builtin_amdgcn_s_setprio(1);
#pragma unroll
        for (int n = 0; n < 4; ++n) {
            bf16x8 k0 = *(const bf16x8*)&Kc[(n * 16 + qi) * 72 + g * 8];
            bf16x8 k1 = *(const bf16x8*)&Kc[(n * 16 + qi) * 72 + 32 + g * 8];
            f32x4 c = f32x4{0.f, 0.f, 0.f, 0.f};
            c = __builtin_amdgcn_mfma_f32_16x16x32_bf16(k0, qf[0], c, 0, 0, 0);
            c = __builtin_amdgcn_mfma_f32_16x16x32_bf16(k1, qf[1], c, 0, 0, 0);
            sacc[n] = c;
        }
        __builtin_amdgcn_s_setprio(0);

        // ---- online softmax in exp2 domain (lane-local row q) ----
        const bool diag = (t == nt - 1);
        float sv[16];
        float tmax = -1e30f;
#pragma unroll
        for (int n = 0; n < 4; ++n)
#pragma unroll
            for (int j = 0; j < 4; ++j) {
                float v = sacc[n][j];
                if (diag && (n * 16 + g * 4 + j > q_rel)) v = -1e30f;
                sv[n * 4 + j] = v;
                tmax = fmaxf(tmax, v);
            }
        tmax = fmaxf(tmax, __shfl_xor(tmax, 16));
        tmax = fmaxf(tmax, __shfl_xor(tmax, 32));
        float mnew = fmaxf(m_prev, tmax);
        float alpha = exp2f(m_prev - mnew);
        float psum = 0.f;
#pragma unroll
        for (int n = 0; n < 4; ++n) {
            float p0 = exp2f(sv[n * 4 + 0] - mnew);
            float p1 = exp2f(sv[n * 4 + 1] - mnew);
            float p2 = exp2f(sv[n * 4 + 2] - mnew);
            float p3 = exp2f(sv[n * 4 + 3] - mnew);
            psum += (p0 + p1) + (p2 + p3);
            *(ushort4*)&Ps[w][qi * 72 + ((n * 16 + g * 4) ^ pswz)] = pack4bf(p0, p1, p2, p3);
        }
        psum += __shfl_xor(psum, 16);
        psum += __shfl_xor(psum, 32);
        lsum = lsum * alpha + psum;
        m_prev = mnew;
#pragma unroll
        for (int n = 0; n < 4; ++n)
#pragma unroll
            for (int j = 0; j < 4; ++j) oacc[n][j] *= alpha;

        // compile-time fence: Ps writes must precede the reads below
        asm volatile("" ::: "memory");

        // ---- O^T += V^T P^T ---- (DS ops complete in-order within a wave)
        __builtin_amdgcn_s_setprio(1);
#pragma unroll
        for (int st = 0; st < 2; ++st) {
            bf16x8 ptf = *(const bf16x8*)&Ps[w][qi * 72 + ((st * 32 + g * 8) ^ pswz)];
#pragma unroll
            for (int n = 0; n < 4; ++n) {
                int d = n * 16 + qi;
                int o = (st * 32 + g * 8) ^ (((d >> 3) & 7) << 3);
                bf16x8 vfr = *(const bf16x8*)&Vc[d * 72 + o];
                oacc[n] = __builtin_amdgcn_mfma_f32_16x16x32_bf16(vfr, ptf, oacc[n], 0, 0, 0);
            }
        }
        __builtin_amdgcn_s_setprio(0);
        __syncthreads();
        cur ^= 1;
    }

    // ---- normalize, transpose via Ps, coalesced O write over own Q rows ----
    {
        float inv = 1.0f / lsum;
#pragma unroll
        for (int n = 0; n < 4; ++n)
            *(ushort4*)&Ps[w][qi * 72 + ((n * 16 + g * 4) ^ pswz)] =
                pack4bf(oacc[n][0] * inv, oacc[n][1] * inv, oacc[n][2] * inv, oacc[n][3] * inv);
        asm volatile("" ::: "memory");
        const int r = lane >> 2;             // q row 0..15
        const int cs = (lane & 3) * 16;      // d start
        const int rswz = (r & 7) << 3;
        bf16x8 o0 = *(const bf16x8*)&Ps[w][r * 72 + (cs ^ rswz)];
        bf16x8 o1 = *(const bf16x8*)&Ps[w][r * 72 + ((cs + 8) ^ rswz)];
        *(bf16x8*)&QKV[(size_t)(rowbase + q0 + r) * S + hd0 + cs] = o0;
        *(bf16x8*)&QKV[(size_t)(rowbase + q0 + r) * S + hd0 + cs + 8] = o1;
    }
}

// ---------- launch ----------
extern "C" void kernel_launch(void* const* d_in, const int* in_sizes, int n_in,
                              void* d_out, int out_size, void* d_ws, size_t ws_size,
                              hipStream_t stream) {
    const float* x  = (const float*)d_in[0];
    const float* Wq = (const float*)d_in[1];
    const float* Wk = (const float*)d_in[2];
    const float* Wv = (const float*)d_in[3];
    const float* Wo = (const float*)d_in[4];
    float* out = (float*)d_out;

    const int WN = 1024 * 1024;

    // workspace: Wqkv_t [3072][1024] (6MB) + Wo_t (2MB) + QKV [4096][3072] (24MB) = 32MB
    unsigned short* ws   = (unsigned short*)d_ws;
    unsigned short* Wqkv = ws;
    unsigned short* Wot  = Wqkv + 3 * WN;
    unsigned short* QKV  = Wot + WN;

    // Q scale: 1/sqrt(64) * log2(e)  (softmax in exp2 domain)
    transpose4_kernel<<<dim3(16, 16, 4), 256, 0, stream>>>(
        Wq, Wk, Wv, Wo, Wqkv, Wqkv + WN, Wqkv + 2 * WN, Wot, 0.125f * 1.4426950408889634f);

    // fused QKV projection: [4096,1024] x [1024,3072] -> [4096,3072]
    gemm_bt<1, 1><<<24 * 32, 256, 0, stream>>>(
        x, Wqkv, QKV, 4096, 3072, 1024, 1024, 3072, 24);

    flash_kernel<<<dim3(32, 32), 256, 0, stream>>>(QKV);

    // output projection: A = O (bf16, Q region of QKV, lda=3072)
    gemm_bt<0, 0><<<8 * 32, 256, 0, stream>>>(
        QKV, Wot, out, 4096, 1024, 1024, 3072, 1024, 8);
}

// Round 7
// 130.921 us; speedup vs baseline: 2.7394x; 1.0474x over previous
//
#include <hip/hip_runtime.h>
#include <cstdint>
#include <cstddef>

// ---------- types ----------
typedef __attribute__((ext_vector_type(8))) __bf16 bf16x8;
typedef __attribute__((ext_vector_type(4))) float f32x4;

// fp32 -> bf16 round-to-nearest-even (manual; used where vector cvt isn't natural)
__device__ __forceinline__ unsigned short f2bf(float x) {
    unsigned int u = __float_as_uint(x);
    u += 0x7fffu + ((u >> 16) & 1u);
    return (unsigned short)(u >> 16);
}

__device__ __forceinline__ ushort4 pack4bf(float a, float b, float c, float d) {
    union { ushort4 v; __bf16 e[4]; } u;
    u.e[0] = (__bf16)a; u.e[1] = (__bf16)b; u.e[2] = (__bf16)c; u.e[3] = (__bf16)d;
    return u.v;
}

typedef const __attribute__((address_space(1))) void* gptr_t;
typedef __attribute__((address_space(3))) void* lptr_t;
__device__ __forceinline__ void gload_lds16(const void* g, void* l) {
    __builtin_amdgcn_global_load_lds((gptr_t)g, (lptr_t)l, 16, 0, 0);
}

// ---------- fused tiled transpose+cast of the 4 weight matrices ----------
// Wt[n][k] = W[k][n] * scale ; D=1024, 64x64 tiles, grid (16,16,4)
__global__ __launch_bounds__(256) void transpose4_kernel(const float* __restrict__ W0,
                                                         const float* __restrict__ W1,
                                                         const float* __restrict__ W2,
                                                         const float* __restrict__ W3,
                                                         unsigned short* __restrict__ T0,
                                                         unsigned short* __restrict__ T1,
                                                         unsigned short* __restrict__ T2,
                                                         unsigned short* __restrict__ T3,
                                                         float s0) {
    __shared__ float Ts[64][65];
    const int D = 1024;
    const int m = blockIdx.z;
    const float* W = (m == 0) ? W0 : (m == 1) ? W1 : (m == 2) ? W2 : W3;
    unsigned short* T = (m == 0) ? T0 : (m == 1) ? T1 : (m == 2) ? T2 : T3;
    const float scale = (m == 0) ? s0 : 1.0f;
    const int kt = blockIdx.y * 64, nt = blockIdx.x * 64;
    const int tid = threadIdx.x;

    {   // read 64x64 f32 tile, coalesced (each thread: 64B along one row)
        const int r = tid >> 2, cs = (tid & 3) * 16;
#pragma unroll
        for (int j = 0; j < 16; j += 4) {
            f32x4 v = *(const f32x4*)&W[(size_t)(kt + r) * D + nt + cs + j];
#pragma unroll
            for (int e = 0; e < 4; ++e) Ts[r][cs + j + e] = v[e];
        }
    }
    __syncthreads();
    {   // write transposed bf16 rows, 32B contiguous per thread
        const int n = tid >> 2, ks = (tid & 3) * 16;
        union { bf16x8 v[2]; __bf16 e[16]; } cv;
#pragma unroll
        for (int j = 0; j < 16; ++j) cv.e[j] = (__bf16)(Ts[ks + j][n] * scale);
        *(bf16x8*)&T[(size_t)(nt + n) * D + kt + ks] = cv.v[0];
        *(bf16x8*)&T[(size_t)(nt + n) * D + kt + ks + 8] = cv.v[1];
    }
}

// ---------- GEMM, C = A * B with Bt = B^T given ----------
// A [M,K] row stride lda (fp32 reg-staged if AF32, else bf16 via global_load_lds),
// Bt [N,K] bf16 row-major (stride K), C [M,N] row stride ldc (bf16 if OUTBF else f32).
// 128x128 tile, BK=32, 4 waves, each wave 64x64 (4x4 fragments of 16x16x32).
// 1D grid, bijective XCD-chunk swizzle (requires gridDim.x % 8 == 0).
template <int AF32, int OUTBF>
__global__ __launch_bounds__(256) void gemm_bt(const void* __restrict__ Ain,
                                               const unsigned short* __restrict__ Bt,
                                               void* __restrict__ Cout,
                                               int M, int N, int K, int lda, int ldc,
                                               int nbx) {
    __shared__ __align__(16) unsigned short Au[128 * 32];
    __shared__ __align__(16) unsigned short Bs[128 * 32];
    const int tid = threadIdx.x;
    const int w = tid >> 6;
    const int lane = tid & 63;

    const int nwg = gridDim.x;
    const int q8 = nwg >> 3;
    const int orig = blockIdx.x;
    const int newlin = (orig & 7) * q8 + (orig >> 3);
    const int by = newlin / nbx;
    const int bx = newlin - by * nbx;
    const int m0 = by * 128;
    const int n0 = bx * 128;
    const int wr = w >> 1, wc = w & 1;

    f32x4 acc[4][4];
#pragma unroll
    for (int i = 0; i < 4; ++i)
#pragma unroll
        for (int j = 0; j < 4; ++j) acc[i][j] = f32x4{0.f, 0.f, 0.f, 0.f};

    const int arow = tid >> 1;
    const int akh = tid & 1;
    const float* A32 = (const float*)Ain;
    f32x4 ar[4];
    if (AF32) {
        const float* s = A32 + (size_t)(m0 + arow) * lda + akh * 16;
#pragma unroll
        for (int j = 0; j < 4; ++j) ar[j] = *(const f32x4*)(s + j * 4);
    }

    for (int kt = 0; kt < K; kt += 32) {
        if (AF32) {
            union { bf16x8 v[2]; __bf16 e[16]; } cv;
#pragma unroll
            for (int j = 0; j < 16; ++j) cv.e[j] = (__bf16)ar[j >> 2][j & 3];
            *(bf16x8*)&Au[arow * 32 + akh * 16] = cv.v[0];
            *(bf16x8*)&Au[arow * 32 + akh * 16 + 8] = cv.v[1];
        } else {
            const unsigned short* A = (const unsigned short*)Ain;
#pragma unroll
            for (int p = 0; p < 2; ++p) {
                int c = p * 4 + w;
                int row = c * 16 + (lane >> 2);
                gload_lds16(A + (size_t)(m0 + row) * lda + kt + (lane & 3) * 8,
                            &Au[c * 512]);
            }
        }
#pragma unroll
        for (int p = 0; p < 2; ++p) {
            int c = p * 4 + w;
            int row = c * 16 + (lane >> 2);
            gload_lds16(Bt + (size_t)(n0 + row) * K + kt + (lane & 3) * 8,
                        &Bs[c * 512]);
        }
        __syncthreads();

        if (AF32 && kt + 32 < K) {
            const float* s = A32 + (size_t)(m0 + arow) * lda + kt + 32 + akh * 16;
#pragma unroll
            for (int j = 0; j < 4; ++j) ar[j] = *(const f32x4*)(s + j * 4);
        }

        bf16x8 af[4], bfr[4];
#pragma unroll
        for (int m = 0; m < 4; ++m)
            af[m] = *(const bf16x8*)&Au[(wr * 64 + m * 16 + (lane & 15)) * 32 +
                                        (lane >> 4) * 8];
#pragma unroll
        for (int n = 0; n < 4; ++n)
            bfr[n] = *(const bf16x8*)&Bs[(wc * 64 + n * 16 + (lane & 15)) * 32 +
                                         (lane >> 4) * 8];
#pragma unroll
        for (int m = 0; m < 4; ++m)
#pragma unroll
            for (int n = 0; n < 4; ++n)
                acc[m][n] = __builtin_amdgcn_mfma_f32_16x16x32_bf16(af[m], bfr[n], acc[m][n], 0, 0, 0);
        __syncthreads();
    }

    const int crow = (lane >> 4) * 4;
    const int ccol = lane & 15;
#pragma unroll
    for (int m = 0; m < 4; ++m) {
#pragma unroll
        for (int n = 0; n < 4; ++n) {
            int r0 = m0 + wr * 64 + m * 16 + crow;
            int c0 = n0 + wc * 64 + n * 16 + ccol;
#pragma unroll
            for (int j = 0; j < 4; ++j) {
                if (OUTBF)
                    ((unsigned short*)Cout)[(size_t)(r0 + j) * ldc + c0] = f2bf(acc[m][n][j]);
                else
                    ((float*)Cout)[(size_t)(r0 + j) * ldc + c0] = acc[m][n][j];
            }
        }
    }
}

// ---------- causal flash attention (swapped-operand, S^T/O^T in registers) ----------
// QKV fused [B*L, 3072] bf16: Q cols [0,1024), K [1024,2048), V [2048,3072).
// Q pre-scaled by log2(e)/sqrt(hd) (softmax runs in exp2 domain).
// O written in-place over Q columns (per-block row ownership).
// Grid (32 bh, 32 qblk): linear%8 = bh%8 -> one head's blocks share an XCD.
// y -> qblk 31-y: heavy blocks dispatch first.
// Ps layout [q][kv] with stride 72 (pad 8): stride = 36 dwords == 4 banks/row,
// so per quarter-wave (g fixed, qi=0..15) every Ps op is bank = 4*qi + const
// -> 2-way max (free). NO XOR swizzle on top (r6's XOR cancelled the padding
// rotation and created a 16-way conflict: 14.65M conflict cycles).
__global__ __launch_bounds__(256) void flash_kernel(unsigned short* __restrict__ QKV) {
    __shared__ __align__(16) unsigned short Ks[2][64 * 72];   // [kv][d], +8 pad
    __shared__ __align__(16) unsigned short Vs[2][64 * 72];   // [d][kv], kv XOR-swizzled
    __shared__ __align__(16) unsigned short Ps[4][16 * 72];   // per-wave P^T as [q][kv]

    const int tid = threadIdx.x;
    const int w = tid >> 6;
    const int lane = tid & 63;
    const int bh = blockIdx.x;          // 0..31 ; XCD = bh % 8
    const int b = bh >> 4, h = bh & 15;
    const int rowbase = b * 2048;
    const int hd0 = h * 64;
    const int S = 3072;

    const int sr = tid >> 3;            // staging: K rows {p*32+sr}
    const int sc = (tid & 7) * 8;       //          cols [sc, sc+8)
    const int vswz = (tid & 7) << 3;    // V store column swizzle

    const int qi = lane & 15;           // this lane's q column
    const int g = lane >> 4;            // lane group: kv sub-rows g*4..g*4+3

    const int qblk = (31 - (int)blockIdx.y) * 64;
    const int q0 = qblk + w * 16;
    const int nt = qblk / 64 + 1;
    const int q_rel = w * 16 + qi;      // q - qblk

    // Q fragments (B-operand), 2 d-steps of 32 over hd=64
    bf16x8 qf[2];
#pragma unroll
    for (int st = 0; st < 2; ++st)
        qf[st] = *(const bf16x8*)(QKV + (size_t)(rowbase + q0 + qi) * S + hd0 +
                                  st * 32 + g * 8);

    float m_prev = -1e30f, lsum = 0.f;
    f32x4 oacc[4];
#pragma unroll
    for (int n = 0; n < 4; ++n) oacc[n] = f32x4{0.f, 0.f, 0.f, 0.f};

    bf16x8 kreg[2], vreg[2];
    // prologue: tile 0 -> regs -> buf0 ; tile 1 -> regs
#pragma unroll
    for (int p = 0; p < 2; ++p) {
        size_t gi = (size_t)(rowbase + p * 32 + sr) * S + hd0 + sc;
        kreg[p] = *(const bf16x8*)(QKV + gi + 1024);
        vreg[p] = *(const bf16x8*)(QKV + gi + 2048);
    }
#pragma unroll
    for (int p = 0; p < 2; ++p) {
        int r = p * 32 + sr;
        *(bf16x8*)&Ks[0][r * 72 + sc] = kreg[p];
        int rs = r ^ vswz;
#pragma unroll
        for (int jj = 0; jj < 8; ++jj)
            Vs[0][(sc + jj) * 72 + rs] = ((const unsigned short*)&vreg[p])[jj];
    }
    if (nt > 1) {
#pragma unroll
        for (int p = 0; p < 2; ++p) {
            size_t gi = (size_t)(rowbase + 64 + p * 32 + sr) * S + hd0 + sc;
            kreg[p] = *(const bf16x8*)(QKV + gi + 1024);
            vreg[p] = *(const bf16x8*)(QKV + gi + 2048);
        }
    }
    __syncthreads();

    int cur = 0;
    for (int t = 0; t < nt; ++t) {
        // ---- write staged regs (tile t+1) to the other buffer; issue t+2 loads ----
        if (t + 1 < nt) {
#pragma unroll
            for (int p = 0; p < 2; ++p) {
                int r = p * 32 + sr;
                *(bf16x8*)&Ks[cur ^ 1][r * 72 + sc] = kreg[p];
                int rs = r ^ vswz;
#pragma unroll
                for (int jj = 0; jj < 8; ++jj)
                    Vs[cur ^ 1][(sc + jj) * 72 + rs] = ((const unsigned short*)&vreg[p])[jj];
            }
            if (t + 2 < nt) {
#pragma unroll
                for (int p = 0; p < 2; ++p) {
                    size_t gi = (size_t)(rowbase + (t + 2) * 64 + p * 32 + sr) * S + hd0 + sc;
                    kreg[p] = *(const bf16x8*)(QKV + gi + 1024);
                    vreg[p] = *(const bf16x8*)(QKV + gi + 2048);
                }
            }
        }

        const unsigned short* Kc = Ks[cur];
        const unsigned short* Vc = Vs[cur];

        // ---- S^T = K Q^T : sacc[n][j] = S[kv0 + n*16 + g*4 + j][q] ----
        f32x4 sacc[4];
        __builtin_amdgcn_s_setprio(1);
#pragma unroll
        for (int n = 0; n < 4; ++n) {
            bf16x8 k0 = *(const bf16x8*)&Kc[(n * 16 + qi) * 72 + g * 8];
            bf16x8 k1 = *(const bf16x8*)&Kc[(n * 16 + qi) * 72 + 32 + g * 8];
            f32x4 c = f32x4{0.f, 0.f, 0.f, 0.f};
            c = __builtin_amdgcn_mfma_f32_16x16x32_bf16(k0, qf[0], c, 0, 0, 0);
            c = __builtin_amdgcn_mfma_f32_16x16x32_bf16(k1, qf[1], c, 0, 0, 0);
            sacc[n] = c;
        }
        __builtin_amdgcn_s_setprio(0);

        // ---- online softmax in exp2 domain (lane-local column q) ----
        const bool diag = (t == nt - 1);
        if (diag) {
#pragma unroll
            for (int n = 0; n < 4; ++n)
#pragma unroll
                for (int j = 0; j < 4; ++j)
                    if (n * 16 + g * 4 + j > q_rel) sacc[n][j] = -1e30f;
        }
        float tmax = -1e30f;
#pragma unroll
        for (int n = 0; n < 4; ++n) {
            float a = fmaxf(fmaxf(sacc[n][0], sacc[n][1]), fmaxf(sacc[n][2], sacc[n][3]));
            tmax = fmaxf(tmax, a);
        }
        tmax = fmaxf(tmax, __shfl_xor(tmax, 16));
        tmax = fmaxf(tmax, __shfl_xor(tmax, 32));

        // defer-max (T13): skip the O/lsum rescale while the tile max stays
        // within 8 of the running max (P values bounded by 2^8; bf16-safe).
        const bool defer = __all(tmax - m_prev <= 8.0f);
        const float mnew = defer ? m_prev : fmaxf(m_prev, tmax);

        float psum = 0.f;
#pragma unroll
        for (int n = 0; n < 4; ++n) {
            float p0 = exp2f(sacc[n][0] - mnew);
            float p1 = exp2f(sacc[n][1] - mnew);
            float p2 = exp2f(sacc[n][2] - mnew);
            float p3 = exp2f(sacc[n][3] - mnew);
            psum += (p0 + p1) + (p2 + p3);
            *(ushort4*)&Ps[w][qi * 72 + n * 16 + g * 4] = pack4bf(p0, p1, p2, p3);
        }
        psum += __shfl_xor(psum, 16);
        psum += __shfl_xor(psum, 32);
        if (!defer) {
            float alpha = exp2f(m_prev - mnew);
            lsum *= alpha;
#pragma unroll
            for (int n = 0; n < 4; ++n)
#pragma unroll
                for (int j = 0; j < 4; ++j) oacc[n][j] *= alpha;
            m_prev = mnew;
        }
        lsum += psum;

        // compile-time fence: Ps writes must precede the reads below
        asm volatile("" ::: "memory");

        // ---- O^T += V^T P^T ---- (DS ops complete in-order within a wave)
        __builtin_amdgcn_s_setprio(1);
#pragma unroll
        for (int st = 0; st < 2; ++st) {
            bf16x8 ptf = *(const bf16x8*)&Ps[w][qi * 72 + st * 32 + g * 8];
#pragma unroll
            for (int n = 0; n < 4; ++n) {
                int d = n * 16 + qi;
                int o = (st * 32 + g * 8) ^ (((d >> 3) & 7) << 3);
                bf16x8 vfr = *(const bf16x8*)&Vc[d * 72 + o];
                oacc[n] = __builtin_amdgcn_mfma_f32_16x16x32_bf16(vfr, ptf, oacc[n], 0, 0, 0);
            }
        }
        __builtin_amdgcn_s_setprio(0);
        __syncthreads();
        cur ^= 1;
    }

    // ---- normalize, transpose via Ps, coalesced O write over own Q rows ----
    {
        float inv = 1.0f / lsum;
#pragma unroll
        for (int n = 0; n < 4; ++n)
            *(ushort4*)&Ps[w][qi * 72 + n * 16 + g * 4] =
                pack4bf(oacc[n][0] * inv, oacc[n][1] * inv, oacc[n][2] * inv, oacc[n][3] * inv);
        asm volatile("" ::: "memory");
        const int r = lane >> 2;             // q row 0..15
        const int cs = (lane & 3) * 16;      // d start
        bf16x8 o0 = *(const bf16x8*)&Ps[w][r * 72 + cs];
        bf16x8 o1 = *(const bf16x8*)&Ps[w][r * 72 + cs + 8];
        *(bf16x8*)&QKV[(size_t)(rowbase + q0 + r) * S + hd0 + cs] = o0;
        *(bf16x8*)&QKV[(size_t)(rowbase + q0 + r) * S + hd0 + cs + 8] = o1;
    }
}

// ---------- launch ----------
extern "C" void kernel_launch(void* const* d_in, const int* in_sizes, int n_in,
                              void* d_out, int out_size, void* d_ws, size_t ws_size,
                              hipStream_t stream) {
    const float* x  = (const float*)d_in[0];
    const float* Wq = (const float*)d_in[1];
    const float* Wk = (const float*)d_in[2];
    const float* Wv = (const float*)d_in[3];
    const float* Wo = (const float*)d_in[4];
    float* out = (float*)d_out;

    const int WN = 1024 * 1024;

    // workspace: Wqkv_t [3072][1024] (6MB) + Wo_t (2MB) + QKV [4096][3072] (24MB) = 32MB
    unsigned short* ws   = (unsigned short*)d_ws;
    unsigned short* Wqkv = ws;
    unsigned short* Wot  = Wqkv + 3 * WN;
    unsigned short* QKV  = Wot + WN;

    // Q scale: 1/sqrt(64) * log2(e)  (softmax in exp2 domain)
    transpose4_kernel<<<dim3(16, 16, 4), 256, 0, stream>>>(
        Wq, Wk, Wv, Wo, Wqkv, Wqkv + WN, Wqkv + 2 * WN, Wot, 0.125f * 1.4426950408889634f);

    // fused QKV projection: [4096,1024] x [1024,3072] -> [4096,3072]
    gemm_bt<1, 1><<<24 * 32, 256, 0, stream>>>(
        x, Wqkv, QKV, 4096, 3072, 1024, 1024, 3072, 24);

    flash_kernel<<<dim3(32, 32), 256, 0, stream>>>(QKV);

    // output projection: A = O (bf16, Q region of QKV, lda=3072)
    gemm_bt<0, 0><<<8 * 32, 256, 0, stream>>>(
        QKV, Wot, out, 4096, 1024, 1024, 3072, 1024, 8);
}